// Round 6
// baseline (5298.580 us; speedup 1.0000x reference)
//
#include <hip/hip_runtime.h>

typedef __attribute__((ext_vector_type(8))) short short8;
typedef __attribute__((ext_vector_type(4))) float f32x4;
typedef unsigned short u16;
typedef unsigned int u32;

static __device__ __forceinline__ float sigf(float x){ return 1.0f/(1.0f+expf(-x)); }

static __device__ __forceinline__ u16 f2b(float f){
    u32 u = __float_as_uint(f);
    u += 0x7FFFu + ((u>>16)&1u);   // RNE
    return (u16)(u>>16);
}
static __device__ __forceinline__ float us2f(u16 s){ return __uint_as_float(((u32)s)<<16); }
static __device__ __forceinline__ float b2f_lo(u32 u){ return __uint_as_float(u<<16); }
static __device__ __forceinline__ float b2f_hi(u32 u){ return __uint_as_float(u & 0xffff0000u); }

// Device-scope write-through stores (sc1): bypass L2, land in LLC.
static __device__ __forceinline__ void st_wt_u16(u16* p, u16 v) {
    asm volatile("global_store_short %0, %1, off sc1" :: "v"(p), "v"((u32)v) : "memory");
}
static __device__ __forceinline__ void st_wt_u32(u32* p, u32 v) {
    asm volatile("global_store_dword %0, %1, off sc1" :: "v"(p), "v"(v) : "memory");
}
// Coherent (bypass L1+L2) load for sentinel polling.
static __device__ __forceinline__ u32 ld_cv(const u32* p){
    u32 v;
    asm volatile("global_load_dword %0, %1, off sc0 sc1\ns_waitcnt vmcnt(0)"
                 : "=v"(v) : "v"(p) : "memory");
    return v;
}

// Dependency wait: lanes tid<n poll base[tid] until nonzero, then block-sync.
static __device__ __forceinline__ void wait_flags(const u32* base, int n) {
    if ((int)threadIdx.x < n) {
        const u32* p = base + threadIdx.x;
        while (ld_cv(p) == 0) __builtin_amdgcn_s_sleep(1);
    }
    __syncthreads();
}

// ---------------- utility / conversion kernels ----------------

__global__ __launch_bounds__(256) void k_zero(float* __restrict__ p, long n) {
    for (long i = (long)blockIdx.x*256 + threadIdx.x; i < n; i += (long)gridDim.x*256) p[i] = 0.0f;
}

__global__ __launch_bounds__(256) void k_f2b(const float4* __restrict__ src,
                                             ushort4* __restrict__ dst, long n4) {
    for (long i = (long)blockIdx.x*256 + threadIdx.x; i < n4; i += (long)gridDim.x*256) {
        float4 v = src[i];
        ushort4 u;
        u.x = f2b(v.x); u.y = f2b(v.y); u.z = f2b(v.z); u.w = f2b(v.w);
        dst[i] = u;
    }
}

__global__ __launch_bounds__(256) void k_wenc(const float* __restrict__ whh, u16* __restrict__ dst) {
    int i = blockIdx.x*256 + threadIdx.x;           // 1,048,576
    int n = i >> 9, k = i & 511;
    int j = n >> 2, q = n & 3;
    dst[i] = f2b(whh[(size_t)(q*512 + j)*512 + k]);
}

__global__ __launch_bounds__(256) void k_awiT(const float* __restrict__ awi, u16* __restrict__ dst) {
    int i = blockIdx.x*256 + threadIdx.x;           // 1,048,576
    int kcol = i >> 10, n = i & 1023;
    dst[i] = f2b(awi[(size_t)n*1024 + kcol]);
}

__global__ __launch_bounds__(256) void k_wdec(const float* __restrict__ dwih,
                                              const float* __restrict__ dwhh,
                                              u16* __restrict__ dst) {
    for (long i = (long)blockIdx.x*256 + threadIdx.x; i < 8388608L; i += (long)gridDim.x*256) {
        int n = (int)(i >> 11), k = (int)(i & 2047);
        int j = n >> 2, q = n & 3;
        float v = (k < 1024) ? dwih[(size_t)(q*1024 + j)*1324 + k]
                             : dwhh[(size_t)(q*1024 + j)*1024 + (k - 1024)];
        dst[i] = f2b(v);
    }
}

__global__ __launch_bounds__(256) void k_xw(const float* __restrict__ table,
                                            const int* __restrict__ idx,
                                            const float* __restrict__ W,
                                            int wstride, int koff,
                                            const float* __restrict__ bias,
                                            u16* __restrict__ outU, int N,
                                            int jmask, int jshift) {
    __shared__ float Xs[32][300];
    int m0 = blockIdx.y * 32;
    int j0 = blockIdx.x * 64;
    for (int i = threadIdx.x; i < 32*300; i += 256) {
        int r = i/300, c = i - r*300;
        Xs[r][c] = table[(size_t)idx[m0+r]*300 + c];
    }
    __syncthreads();
    int tx = threadIdx.x & 63, ty = threadIdx.x >> 6;
    int jj = j0 + tx;
    const float* wr = W + (size_t)jj*wstride + koff;
    float acc[8] = {0,0,0,0,0,0,0,0};
    for (int k = 0; k < 300; ++k) {
        float w = wr[k];
#pragma unroll
        for (int mi = 0; mi < 8; ++mi) acc[mi] += Xs[ty*8+mi][k] * w;
    }
    float bv = bias[jj];
    int col = ((jj & jmask) << 2) | (jj >> jshift);
#pragma unroll
    for (int mi = 0; mi < 8; ++mi)
        outU[(size_t)(m0 + ty*8 + mi)*N + col] = f2b(acc[mi] + bv);
}

// ---------------- encoder ----------------
__global__ __launch_bounds__(512) void k_enc(
    const u16* __restrict__ Xf, const u16* __restrict__ Xb,
    const u16* __restrict__ WencB,
    u16* __restrict__ encBX, float* __restrict__ cfin,
    u32* __restrict__ sentE)
{
    __shared__ float SH[2304];
    const int tid = threadIdx.x;
    const int bid = blockIdx.x;
    const int wv = tid >> 6, lane = tid & 63;
    const int gwave = bid*8 + wv;
    const int lr = lane & 15, lk8 = (lane >> 4)*8;
    const int b_l = lane & 15, jjq = lane >> 4;
    const int g0 = bid & 48;

    const int dir = gwave >> 8;
    const int mt = (gwave >> 7) & 1;
    const int nt = gwave & 127;
    const int m0 = mt*16, n0 = nt*16;
    const u16* Bw = WencB + (size_t)dir*1048576 + (size_t)(n0+lr)*512 + lk8;
    const u16* Xd = dir ? Xb : Xf;
    float* T = SH + wv*272;
    const int bb = m0 + b_l;
    const int j = nt*4 + jjq;
    float creg = 0.f;
    for (int t = 0; t < 64; ++t) {
        if (t > 0) wait_flags(sentE + (t-1)*64 + g0, 16);
        const int rslot = (t==0) ? 0 : (dir ? (65-t) : t);
        const u16* Ah = encBX + (size_t)rslot*32768 + (size_t)(m0+lr)*1024 + dir*512 + lk8;
        f32x4 acc = {0.f,0.f,0.f,0.f};
#pragma unroll
        for (int i = 0; i < 16; ++i) {
            short8 av = *(const short8*)(Ah + i*32);
            short8 bv = *(const short8*)(Bw + i*32);
            acc = __builtin_amdgcn_mfma_f32_16x16x32_bf16(av, bv, acc, 0, 0, 0);
        }
        {
            const int rb = (lane>>4)*4;
#pragma unroll
            for (int r = 0; r < 4; ++r) T[(rb+r)*17 + (lane&15)] = acc[r];
        }
        __builtin_amdgcn_sched_barrier(0);
        const int s = dir ? (63-t) : t;
        ushort4 xr = *(const ushort4*)(Xd + (size_t)(s*32+bb)*2048 + n0 + jjq*4);
        float gi = T[b_l*17 + jjq*4 + 0] + us2f(xr.x);
        float gf = T[b_l*17 + jjq*4 + 1] + us2f(xr.y);
        float gg = T[b_l*17 + jjq*4 + 2] + us2f(xr.z);
        float go = T[b_l*17 + jjq*4 + 3] + us2f(xr.w);
        float c2 = sigf(gf)*creg + sigf(gi)*tanhf(gg);
        float h2 = sigf(go)*tanhf(c2);
        creg = c2;
        st_wt_u16(encBX + (size_t)(s+1)*32768 + (size_t)bb*1024 + dir*512 + j, f2b(h2));
        __syncthreads();
        if (tid == 0) st_wt_u32(sentE + t*64 + bid, 1u);
    }
    cfin[dir*16384 + bb*512 + j] = creg;
}

// ---------------- pack ----------------
__global__ __launch_bounds__(256) void k_pack(const u16* __restrict__ encBX,
                                              u16* __restrict__ Hd) {
    for (int gt = blockIdx.x*256 + threadIdx.x; gt < 32768; gt += 16384) {
        int b = gt >> 10, jj2 = gt & 1023;
        int d = jj2 & 1, k = jj2 >> 1;
        Hd[(size_t)b*1024 + jj2] = encBX[(size_t)(d ? 1 : 64)*32768 + (size_t)b*1024 + d*512 + k];
        Hd[(size_t)64*32768 + gt] = 0;
    }
}

// ---------------- encP GEMM ----------------
__global__ __launch_bounds__(256) void k_mid(const u16* __restrict__ encBX,
                                             const u16* __restrict__ awiTB,
                                             u16* __restrict__ encPB) {
    const int wv = threadIdx.x >> 6, lane = threadIdx.x & 63;
    const int lr = lane & 15, lk8 = (lane >> 4)*8;
    const u16* Abase = encBX + 32768;
#pragma unroll
    for (int ii = 0; ii < 4; ++ii) {
        int id = (blockIdx.x*4 + wv)*4 + ii;
        int mt2 = id >> 6, nt2 = id & 63;
        int m0 = mt2*16, n0 = nt2*16;
        const u16* Ar = Abase + (size_t)(m0+lr)*1024 + lk8;
        const u16* Br = awiTB + (size_t)(n0+lr)*1024 + lk8;
        f32x4 acc = {0.f,0.f,0.f,0.f};
#pragma unroll 8
        for (int i = 0; i < 32; ++i) {
            short8 av = *(const short8*)(Ar + i*32);
            short8 bv = *(const short8*)(Br + i*32);
            acc = __builtin_amdgcn_mfma_f32_16x16x32_bf16(av, bv, acc, 0, 0, 0);
        }
        int col = n0 + (lane&15);
        int rb = m0 + (lane>>4)*4;
#pragma unroll
        for (int r = 0; r < 4; ++r)
            encPB[(size_t)(rb+r)*1024 + col] = f2b(acc[r]);
    }
}

// ---------------- decoder ----------------
__global__ __launch_bounds__(512) void k_dec(
    const u16* __restrict__ Xe,
    const u16* __restrict__ awoB, const u16* __restrict__ WdecB,
    const u16* __restrict__ encBX, const u16* __restrict__ encPB,
    u16* __restrict__ Hd, u16* __restrict__ Stb, u16* __restrict__ Ctb,
    const float* __restrict__ cfin,
    u32* __restrict__ sentSt, u32* __restrict__ sentCt, u32* __restrict__ sentH,
    u16* __restrict__ HsB)
{
    __shared__ float SH[2304];
    const int tid = threadIdx.x;
    const int bid = blockIdx.x;
    const int wv = tid >> 6, lane = tid & 63;
    const int gwave = bid*8 + wv;
    const int lr = lane & 15, lk8 = (lane >> 4)*8;
    const int b_l = lane & 15, jjq = lane >> 4;

    const int nt4 = gwave >> 1, mt4 = gwave & 1;
    const int n0d = nt4*16, m0d = mt4*16;
    const int bbd = m0d + b_l;
    const int jd = nt4*4 + jjq;
    float cdec = cfin[(jd&1)*16384 + bbd*512 + (jd>>1)];

    for (int t = 0; t < 63; ++t) {
        if (bid < 32) {
            if (t > 0) wait_flags(sentH + t*64, 64);
            const int bbb = bid;
            float* hsh = SH; float* red = SH + 1024; float* sc = SH + 1536;
            {
                u32 u = ((const u32*)Hd)[(size_t)t*16384 + bbb*512 + tid];
                hsh[2*tid]   = b2f_lo(u);
                hsh[2*tid+1] = b2f_hi(u);
            }
            __syncthreads();
            {
                int s = tid >> 3, p = tid & 7;
                const uint4* ep = (const uint4*)(encPB + (size_t)(s*32+bbb)*1024 + p*128);
                const float* hk = hsh + p*128;
                float a0=0,a1=0,a2=0,a3=0;
#pragma unroll 4
                for (int q8 = 0; q8 < 16; ++q8) {
                    uint4 u = ep[q8];
                    a0 += b2f_lo(u.x)*hk[q8*8+0] + b2f_hi(u.x)*hk[q8*8+1];
                    a1 += b2f_lo(u.y)*hk[q8*8+2] + b2f_hi(u.y)*hk[q8*8+3];
                    a2 += b2f_lo(u.z)*hk[q8*8+4] + b2f_hi(u.z)*hk[q8*8+5];
                    a3 += b2f_lo(u.w)*hk[q8*8+6] + b2f_hi(u.w)*hk[q8*8+7];
                }
                red[tid] = (a0+a1)+(a2+a3);
            }
            __syncthreads();
            if (tid < 64) {
                float v = 0;
#pragma unroll
                for (int pp = 0; pp < 8; ++pp) v += red[tid*8+pp];
                float m = v;
                for (int off = 32; off; off >>= 1) m = fmaxf(m, __shfl_xor(m, off));
                float e = expf(v - m);
                float ss = e;
                for (int off = 32; off; off >>= 1) ss += __shfl_xor(ss, off);
                sc[tid] = e / ss;
            }
            __syncthreads();
            {
                float st0 = 0, st1 = 0;
                const u32* eb = (const u32*)encBX + 16384 + bbb*512 + tid;
#pragma unroll 4
                for (int s2 = 0; s2 < 64; ++s2) {
                    u32 u = eb[(size_t)s2*16384];
                    float w = sc[s2];
                    st0 += w*b2f_lo(u); st1 += w*b2f_hi(u);
                }
                u32 pk = (u32)f2b(st0) | ((u32)f2b(st1) << 16);
                st_wt_u32((u32*)Stb + (size_t)t*16384 + bbb*512 + tid, pk);
            }
            __syncthreads();
            if (tid == 0) st_wt_u32(sentSt + t*64 + bid, 1u);
        }

        wait_flags(sentSt + t*64, 32);
        if (t > 0) wait_flags(sentH + t*64, 64);
        {
            const int nt3 = bid;
            const int mt3 = wv >> 2, kq = wv & 3;
            const int m0 = mt3*16, n0 = nt3*16;
            const u16* Br = awoB + (size_t)(n0+lr)*2048 + kq*512 + lk8;
            const u16* As  = Stb + (size_t)t*32768 + (size_t)(m0+lr)*1024 + kq*512 + lk8;
            const u16* Ah2 = Hd  + (size_t)t*32768 + (size_t)(m0+lr)*1024 + (kq-2)*512 + lk8;
            const u16* Ar = (kq < 2) ? As : Ah2;
            f32x4 acc = {0.f,0.f,0.f,0.f};
#pragma unroll 4
            for (int i = 0; i < 16; ++i) {
                short8 av = *(const short8*)(Ar + i*32);
                short8 bv = *(const short8*)(Br + i*32);
                acc = __builtin_amdgcn_mfma_f32_16x16x32_bf16(av, bv, acc, 0, 0, 0);
            }
            float* PH = SH + wv*256;
#pragma unroll
            for (int r = 0; r < 4; ++r) PH[lane*4 + r] = acc[r];
            __syncthreads();
            if (kq == 0) {
#pragma unroll
                for (int r = 0; r < 4; ++r) {
                    float sum = SH[wv*256 + lane*4 + r] + SH[(wv+1)*256 + lane*4 + r]
                              + SH[(wv+2)*256 + lane*4 + r] + SH[(wv+3)*256 + lane*4 + r];
                    int bq = m0 + (lane>>4)*4 + r;
                    st_wt_u16(Ctb + (size_t)t*32768 + (size_t)bq*1024 + n0 + (lane&15),
                              f2b(tanhf(sum)));
                }
            }
            __syncthreads();
            if (tid == 0) st_wt_u32(sentCt + t*64 + bid, 1u);
        }

        wait_flags(sentCt + t*64, 64);
        {
            const u16* Br  = WdecB + (size_t)(n0d+lr)*2048 + lk8;
            const u16* Ac  = Ctb + (size_t)t*32768 + (size_t)(m0d+lr)*1024 + lk8;
            const u16* Ah3 = Hd  + (size_t)t*32768 + (size_t)(m0d+lr)*1024 + lk8;
            f32x4 acc = {0.f,0.f,0.f,0.f};
#pragma unroll 4
            for (int i = 0; i < 32; ++i) {
                short8 av = *(const short8*)(Ac + i*32);
                short8 bv = *(const short8*)(Br + i*32);
                acc = __builtin_amdgcn_mfma_f32_16x16x32_bf16(av, bv, acc, 0, 0, 0);
            }
#pragma unroll 4
            for (int i = 0; i < 32; ++i) {
                short8 av = *(const short8*)(Ah3 + i*32);
                short8 bv = *(const short8*)(Br + 1024 + i*32);
                acc = __builtin_amdgcn_mfma_f32_16x16x32_bf16(av, bv, acc, 0, 0, 0);
            }
            float* T = SH + wv*272;
            {
                const int rb = (lane>>4)*4;
#pragma unroll
                for (int r = 0; r < 4; ++r) T[(rb+r)*17 + (lane&15)] = acc[r];
            }
            __builtin_amdgcn_sched_barrier(0);
            ushort4 xr = *(const ushort4*)(Xe + (size_t)(t*32+bbd)*4096 + n0d + jjq*4);
            float gi = T[b_l*17 + jjq*4 + 0] + us2f(xr.x);
            float gf = T[b_l*17 + jjq*4 + 1] + us2f(xr.y);
            float gg = T[b_l*17 + jjq*4 + 2] + us2f(xr.z);
            float go = T[b_l*17 + jjq*4 + 3] + us2f(xr.w);
            float c2 = sigf(gf)*cdec + sigf(gi)*tanhf(gg);
            float h2 = sigf(go)*tanhf(c2);
            cdec = c2;
            st_wt_u16(Hd + (size_t)(t+1)*32768 + (size_t)bbd*1024 + jd, f2b(h2));
            HsB[((size_t)t*32 + bbd)*1024 + jd] = f2b(h2);
            __syncthreads();
            if (tid == 0) st_wt_u32(sentH + (t+1)*64 + bid, 1u);
        }
    }
}

// ---------------- generator GEMM ----------------
__global__ __launch_bounds__(256) void k_gemm_gen(const short* __restrict__ A,
                                                  const short* __restrict__ B,
                                                  const float* __restrict__ genb,
                                                  float* __restrict__ out) {
    int wave = threadIdx.x >> 6;
    int lane = threadIdx.x & 63;
    int tile = blockIdx.x * 4 + wave;
    int mt = tile & 31;
    int nt = tile >> 5;
    int m0 = mt*64, n0 = nt*64;
    int lr = lane & 15;
    int lk = (lane >> 4)*8;
    f32x4 acc[4][4] = {};
    for (int k0 = 0; k0 < 1024; k0 += 32) {
        short8 a[4], bfr[4];
#pragma unroll
        for (int mi = 0; mi < 4; ++mi)
            a[mi] = *(const short8*)(A + (long)(m0 + mi*16 + lr)*1024 + k0 + lk);
#pragma unroll
        for (int ni = 0; ni < 4; ++ni)
            bfr[ni] = *(const short8*)(B + (long)(n0 + ni*16 + lr)*1024 + k0 + lk);
#pragma unroll
        for (int mi = 0; mi < 4; ++mi)
#pragma unroll
            for (int ni = 0; ni < 4; ++ni)
                acc[mi][ni] = __builtin_amdgcn_mfma_f32_16x16x32_bf16(a[mi], bfr[ni], acc[mi][ni], 0, 0, 0);
    }
    int dcol = lane & 15;
    int drow = (lane >> 4)*4;
#pragma unroll
    for (int mi = 0; mi < 4; ++mi) {
        int mbase = m0 + mi*16 + drow;
#pragma unroll
        for (int ni = 0; ni < 4; ++ni) {
            int n = n0 + ni*16 + dcol;
            float bv = genb[n];
            f32x4 v = acc[mi][ni];
#pragma unroll
            for (int r = 0; r < 4; ++r) {
                int m = mbase + r;
                if (m < 2016) out[(long)(m + 32)*32000 + n] = v[r] + bv;
            }
        }
    }
}

// ---------------- log-softmax ----------------
__global__ __launch_bounds__(256) void k_lsm(float* __restrict__ out) {
    long row = 32 + blockIdx.x;
    float* p = out + row*32000L;
    float4* p4 = (float4*)p;
    int tid = threadIdx.x;
    __shared__ float sm[4];
    __shared__ float ss[4];
    float m = -1e30f;
    for (int i = tid; i < 8000; i += 256) {
        float4 v = p4[i];
        m = fmaxf(m, fmaxf(fmaxf(v.x, v.y), fmaxf(v.z, v.w)));
    }
    for (int off = 32; off; off >>= 1) m = fmaxf(m, __shfl_xor(m, off));
    if ((tid & 63) == 0) sm[tid >> 6] = m;
    __syncthreads();
    m = fmaxf(fmaxf(sm[0], sm[1]), fmaxf(sm[2], sm[3]));
    float s = 0;
    for (int i = tid; i < 8000; i += 256) {
        float4 v = p4[i];
        s += expf(v.x - m) + expf(v.y - m) + expf(v.z - m) + expf(v.w - m);
    }
    for (int off = 32; off; off >>= 1) s += __shfl_xor(s, off);
    if ((tid & 63) == 0) ss[tid >> 6] = s;
    __syncthreads();
    s = ss[0] + ss[1] + ss[2] + ss[3];
    float lse = m + logf(s);
    for (int i = tid; i < 8000; i += 256) {
        float4 v = p4[i];
        v.x -= lse; v.y -= lse; v.z -= lse; v.w -= lse;
        p4[i] = v;
    }
}

// ---------------- launch ----------------

extern "C" void kernel_launch(void* const* d_in, const int* in_sizes, int n_in,
                              void* d_out, int out_size, void* d_ws, size_t ws_size,
                              hipStream_t stream) {
    const float* eemb  = (const float*)d_in[0];
    const float* ewihf = (const float*)d_in[1];
    const float* ewhhf = (const float*)d_in[2];
    const float* ebf   = (const float*)d_in[3];
    const float* ewihb = (const float*)d_in[4];
    const float* ewhhb = (const float*)d_in[5];
    const float* ebb   = (const float*)d_in[6];
    const float* awi   = (const float*)d_in[7];
    const float* awo   = (const float*)d_in[8];
    const float* dwih  = (const float*)d_in[9];
    const float* dwhh  = (const float*)d_in[10];
    const float* db    = (const float*)d_in[11];
    const float* demb  = (const float*)d_in[12];
    const float* genw  = (const float*)d_in[13];
    const float* genb  = (const float*)d_in[14];
    const int* srci    = (const int*)d_in[15];
    const int* trgi    = (const int*)d_in[16];
    float* out = (float*)d_out;

    float* F = (float*)d_ws;
    u32* S       = (u32*)F;
    u32* sentE   = S;                      // 64 x 64
    u32* sentSt  = S + 4096;               // 63 x 64
    u32* sentCt  = S + 8192;               // 63 x 64
    u32* sentH   = S + 12288;              // 64 x 64
    float* cfin  = F + 16384;              // 32768 floats
    u16*   U     = (u16*)(F + 49152);

    u16* Xf_    = U;                       // 2048x2048
    u16* Xb_    = U + 4194304u;            // 2048x2048
    u16* Xe_    = U + 8388608u;            // 2016x4096
    u16* WencB  = U + 16646144u;           // 2 x 2048x512
    u16* awiTB  = U + 18743296u;           // 1024x1024
    u16* awoB   = U + 19791872u;           // 1024x2048
    u16* WdecB  = U + 21889024u;           // 4096x2048
    u16* genw_b = U + 30277632u;           // 32000x1024
    u16* encBX  = U + 63045632u;           // 65 x 32x1024
    u16* Hd     = U + 65175552u;           // 65 x 32x1024
    u16* Stb    = U + 67305472u;           // 63 x 32x1024
    u16* Ctb    = U + 69369856u;           // 63 x 32x1024
    u16* encPB  = U + 71434240u;           // 2048x1024

    k_zero<<<64, 256, 0, stream>>>(F, 16384);
    k_zero<<<64, 256, 0, stream>>>((float*)encBX, 16384);
    k_zero<<<2048, 256, 0, stream>>>(out, 1024000L);

    k_xw<<<dim3(32, 64), 256, 0, stream>>>(eemb, srci, ewihf, 300, 0, ebf, Xf_, 2048, 511, 9);
    k_xw<<<dim3(32, 64), 256, 0, stream>>>(eemb, srci, ewihb, 300, 0, ebb, Xb_, 2048, 511, 9);
    k_xw<<<dim3(64, 63), 256, 0, stream>>>(demb, trgi, dwih, 1324, 1024, db, Xe_, 4096, 1023, 10);

    k_wenc<<<4096, 256, 0, stream>>>(ewhhf, WencB);
    k_wenc<<<4096, 256, 0, stream>>>(ewhhb, WencB + 1048576u);
    k_awiT<<<4096, 256, 0, stream>>>(awi, awiTB);
    k_f2b<<<2048, 256, 0, stream>>>((const float4*)awo, (ushort4*)awoB, 524288L);
    k_wdec<<<8192, 256, 0, stream>>>(dwih, dwhh, WdecB);
    k_f2b<<<8192, 256, 0, stream>>>((const float4*)genw, (ushort4*)genw_b, 8192000L);

    k_enc<<<64, 512, 0, stream>>>(Xf_, Xb_, WencB, encBX, cfin, sentE);
    k_pack<<<64, 256, 0, stream>>>(encBX, Hd);
    k_mid<<<512, 256, 0, stream>>>(encBX, awiTB, encPB);
    k_dec<<<64, 512, 0, stream>>>(Xe_, awoB, WdecB, encBX, encPB,
                                  Hd, Stb, Ctb, cfin, sentSt, sentCt, sentH, Hd + 32768u);

    k_gemm_gen<<<4000, 256, 0, stream>>>((const short*)(Hd + 32768u), (const short*)genw_b, genb, out);
    k_lsm<<<2016, 256, 0, stream>>>(out);
}

// Round 7
// 5156.779 us; speedup vs baseline: 1.0275x; 1.0275x over previous
//
#include <hip/hip_runtime.h>

typedef __attribute__((ext_vector_type(8))) short short8;
typedef __attribute__((ext_vector_type(4))) float f32x4;
typedef unsigned short u16;
typedef unsigned int u32;

static __device__ __forceinline__ float sigf(float x){ return 1.0f/(1.0f+expf(-x)); }

static __device__ __forceinline__ u16 f2b(float f){
    u32 u = __float_as_uint(f);
    u += 0x7FFFu + ((u>>16)&1u);   // RNE
    return (u16)(u>>16);
}
static __device__ __forceinline__ float us2f(u16 s){ return __uint_as_float(((u32)s)<<16); }
static __device__ __forceinline__ float b2f_lo(u32 u){ return __uint_as_float(u<<16); }
static __device__ __forceinline__ float b2f_hi(u32 u){ return __uint_as_float(u & 0xffff0000u); }

// Device-scope write-through stores (sc1): bypass L2, land at device-coherent point.
static __device__ __forceinline__ void st_wt_u16(u16* p, u16 v) {
    asm volatile("global_store_short %0, %1, off sc1" :: "v"(p), "v"((u32)v) : "memory");
}
static __device__ __forceinline__ void st_wt_u32(u32* p, u32 v) {
    asm volatile("global_store_dword %0, %1, off sc1" :: "v"(p), "v"(v) : "memory");
}
// Coherent (bypass L1+L2) load for sentinel polling.
static __device__ __forceinline__ u32 ld_cv(const u32* p){
    u32 v;
    asm volatile("global_load_dword %0, %1, off sc0 sc1\ns_waitcnt vmcnt(0)"
                 : "=v"(v) : "v"(p) : "memory");
    return v;
}

// Short dependent-FMA spin: keeps the VALU pipe busy between polls so the
// power governor holds boost clocks (DVFS hypothesis, r7 experiment).
static __device__ __forceinline__ void hot_spin() {
    float x = 1.0f;
#pragma unroll
    for (int i = 0; i < 16; ++i) x = __builtin_fmaf(x, 1.0000001f, 1.0e-7f);
    asm volatile("" :: "v"(x));
}

// Dependency wait: lanes tid<n poll base[tid] until nonzero, then block-sync.
static __device__ __forceinline__ void wait_flags(const u32* base, int n) {
    if ((int)threadIdx.x < n) {
        const u32* p = base + threadIdx.x;
        while (ld_cv(p) == 0) hot_spin();
    }
    __syncthreads();
}

// Heater: pure FMA burn until all 64 flags at base[0..63] are set, then exit.
static __device__ __forceinline__ void heater(const u32* base) {
    const int lane = threadIdx.x & 63;
    const u32* p = base + lane;
    for (;;) {
        float x = 1.0f;
#pragma unroll 4
        for (int i = 0; i < 512; ++i) x = __builtin_fmaf(x, 1.0000001f, 1.0e-7f);
        asm volatile("" :: "v"(x));
        if (__all(ld_cv(p) != 0)) break;
    }
}

// ---------------- utility / conversion kernels ----------------

__global__ __launch_bounds__(256) void k_zero(float* __restrict__ p, long n) {
    for (long i = (long)blockIdx.x*256 + threadIdx.x; i < n; i += (long)gridDim.x*256) p[i] = 0.0f;
}

__global__ __launch_bounds__(256) void k_f2b(const float4* __restrict__ src,
                                             ushort4* __restrict__ dst, long n4) {
    for (long i = (long)blockIdx.x*256 + threadIdx.x; i < n4; i += (long)gridDim.x*256) {
        float4 v = src[i];
        ushort4 u;
        u.x = f2b(v.x); u.y = f2b(v.y); u.z = f2b(v.z); u.w = f2b(v.w);
        dst[i] = u;
    }
}

__global__ __launch_bounds__(256) void k_wenc(const float* __restrict__ whh, u16* __restrict__ dst) {
    int i = blockIdx.x*256 + threadIdx.x;           // 1,048,576
    int n = i >> 9, k = i & 511;
    int j = n >> 2, q = n & 3;
    dst[i] = f2b(whh[(size_t)(q*512 + j)*512 + k]);
}

__global__ __launch_bounds__(256) void k_awiT(const float* __restrict__ awi, u16* __restrict__ dst) {
    int i = blockIdx.x*256 + threadIdx.x;           // 1,048,576
    int kcol = i >> 10, n = i & 1023;
    dst[i] = f2b(awi[(size_t)n*1024 + kcol]);
}

__global__ __launch_bounds__(256) void k_wdec(const float* __restrict__ dwih,
                                              const float* __restrict__ dwhh,
                                              u16* __restrict__ dst) {
    for (long i = (long)blockIdx.x*256 + threadIdx.x; i < 8388608L; i += (long)gridDim.x*256) {
        int n = (int)(i >> 11), k = (int)(i & 2047);
        int j = n >> 2, q = n & 3;
        float v = (k < 1024) ? dwih[(size_t)(q*1024 + j)*1324 + k]
                             : dwhh[(size_t)(q*1024 + j)*1024 + (k - 1024)];
        dst[i] = f2b(v);
    }
}

__global__ __launch_bounds__(256) void k_xw(const float* __restrict__ table,
                                            const int* __restrict__ idx,
                                            const float* __restrict__ W,
                                            int wstride, int koff,
                                            const float* __restrict__ bias,
                                            u16* __restrict__ outU, int N,
                                            int jmask, int jshift) {
    __shared__ float Xs[32][300];
    int m0 = blockIdx.y * 32;
    int j0 = blockIdx.x * 64;
    for (int i = threadIdx.x; i < 32*300; i += 256) {
        int r = i/300, c = i - r*300;
        Xs[r][c] = table[(size_t)idx[m0+r]*300 + c];
    }
    __syncthreads();
    int tx = threadIdx.x & 63, ty = threadIdx.x >> 6;
    int jj = j0 + tx;
    const float* wr = W + (size_t)jj*wstride + koff;
    float acc[8] = {0,0,0,0,0,0,0,0};
    for (int k = 0; k < 300; ++k) {
        float w = wr[k];
#pragma unroll
        for (int mi = 0; mi < 8; ++mi) acc[mi] += Xs[ty*8+mi][k] * w;
    }
    float bv = bias[jj];
    int col = ((jj & jmask) << 2) | (jj >> jshift);
#pragma unroll
    for (int mi = 0; mi < 8; ++mi)
        outU[(size_t)(m0 + ty*8 + mi)*N + col] = f2b(acc[mi] + bv);
}

// ---------------- encoder (blocks 0-63 work, 64-255 heat) ----------------
__global__ __launch_bounds__(512) void k_enc(
    const u16* __restrict__ Xf, const u16* __restrict__ Xb,
    const u16* __restrict__ WencB,
    u16* __restrict__ encBX, float* __restrict__ cfin,
    u32* __restrict__ sentE)
{
    __shared__ float SH[2304];
    const int tid = threadIdx.x;
    const int bid = blockIdx.x;
    if (bid >= 64) { heater(sentE + 63*64); return; }

    const int wv = tid >> 6, lane = tid & 63;
    const int gwave = bid*8 + wv;
    const int lr = lane & 15, lk8 = (lane >> 4)*8;
    const int b_l = lane & 15, jjq = lane >> 4;
    const int g0 = bid & 48;

    const int dir = gwave >> 8;
    const int mt = (gwave >> 7) & 1;
    const int nt = gwave & 127;
    const int m0 = mt*16, n0 = nt*16;
    const u16* Bw = WencB + (size_t)dir*1048576 + (size_t)(n0+lr)*512 + lk8;
    const u16* Xd = dir ? Xb : Xf;
    float* T = SH + wv*272;
    const int bb = m0 + b_l;
    const int j = nt*4 + jjq;
    float creg = 0.f;
    for (int t = 0; t < 64; ++t) {
        if (t > 0) wait_flags(sentE + (t-1)*64 + g0, 16);
        const int rslot = (t==0) ? 0 : (dir ? (65-t) : t);
        const u16* Ah = encBX + (size_t)rslot*32768 + (size_t)(m0+lr)*1024 + dir*512 + lk8;
        f32x4 acc = {0.f,0.f,0.f,0.f};
#pragma unroll
        for (int i = 0; i < 16; ++i) {
            short8 av = *(const short8*)(Ah + i*32);
            short8 bv = *(const short8*)(Bw + i*32);
            acc = __builtin_amdgcn_mfma_f32_16x16x32_bf16(av, bv, acc, 0, 0, 0);
        }
        {
            const int rb = (lane>>4)*4;
#pragma unroll
            for (int r = 0; r < 4; ++r) T[(rb+r)*17 + (lane&15)] = acc[r];
        }
        __builtin_amdgcn_sched_barrier(0);
        const int s = dir ? (63-t) : t;
        ushort4 xr = *(const ushort4*)(Xd + (size_t)(s*32+bb)*2048 + n0 + jjq*4);
        float gi = T[b_l*17 + jjq*4 + 0] + us2f(xr.x);
        float gf = T[b_l*17 + jjq*4 + 1] + us2f(xr.y);
        float gg = T[b_l*17 + jjq*4 + 2] + us2f(xr.z);
        float go = T[b_l*17 + jjq*4 + 3] + us2f(xr.w);
        float c2 = sigf(gf)*creg + sigf(gi)*tanhf(gg);
        float h2 = sigf(go)*tanhf(c2);
        creg = c2;
        st_wt_u16(encBX + (size_t)(s+1)*32768 + (size_t)bb*1024 + dir*512 + j, f2b(h2));
        __syncthreads();
        if (tid == 0) st_wt_u32(sentE + t*64 + bid, 1u);
    }
    cfin[dir*16384 + bb*512 + j] = creg;
}

// ---------------- pack ----------------
__global__ __launch_bounds__(256) void k_pack(const u16* __restrict__ encBX,
                                              u16* __restrict__ Hd) {
    for (int gt = blockIdx.x*256 + threadIdx.x; gt < 32768; gt += 16384) {
        int b = gt >> 10, jj2 = gt & 1023;
        int d = jj2 & 1, k = jj2 >> 1;
        Hd[(size_t)b*1024 + jj2] = encBX[(size_t)(d ? 1 : 64)*32768 + (size_t)b*1024 + d*512 + k];
        Hd[(size_t)64*32768 + gt] = 0;
    }
}

// ---------------- encP GEMM ----------------
__global__ __launch_bounds__(256) void k_mid(const u16* __restrict__ encBX,
                                             const u16* __restrict__ awiTB,
                                             u16* __restrict__ encPB) {
    const int wv = threadIdx.x >> 6, lane = threadIdx.x & 63;
    const int lr = lane & 15, lk8 = (lane >> 4)*8;
    const u16* Abase = encBX + 32768;
#pragma unroll
    for (int ii = 0; ii < 4; ++ii) {
        int id = (blockIdx.x*4 + wv)*4 + ii;
        int mt2 = id >> 6, nt2 = id & 63;
        int m0 = mt2*16, n0 = nt2*16;
        const u16* Ar = Abase + (size_t)(m0+lr)*1024 + lk8;
        const u16* Br = awiTB + (size_t)(n0+lr)*1024 + lk8;
        f32x4 acc = {0.f,0.f,0.f,0.f};
#pragma unroll 8
        for (int i = 0; i < 32; ++i) {
            short8 av = *(const short8*)(Ar + i*32);
            short8 bv = *(const short8*)(Br + i*32);
            acc = __builtin_amdgcn_mfma_f32_16x16x32_bf16(av, bv, acc, 0, 0, 0);
        }
        int col = n0 + (lane&15);
        int rb = m0 + (lane>>4)*4;
#pragma unroll
        for (int r = 0; r < 4; ++r)
            encPB[(size_t)(rb+r)*1024 + col] = f2b(acc[r]);
    }
}

// ---------------- decoder (blocks 0-63 work, 64-255 heat) ----------------
__global__ __launch_bounds__(512) void k_dec(
    const u16* __restrict__ Xe,
    const u16* __restrict__ awoB, const u16* __restrict__ WdecB,
    const u16* __restrict__ encBX, const u16* __restrict__ encPB,
    u16* __restrict__ Hd, u16* __restrict__ Stb, u16* __restrict__ Ctb,
    const float* __restrict__ cfin,
    u32* __restrict__ sentSt, u32* __restrict__ sentCt, u32* __restrict__ sentH)
{
    __shared__ float SH[2304];
    const int tid = threadIdx.x;
    const int bid = blockIdx.x;
    if (bid >= 64) { heater(sentH + 63*64); return; }

    const int wv = tid >> 6, lane = tid & 63;
    const int gwave = bid*8 + wv;
    const int lr = lane & 15, lk8 = (lane >> 4)*8;
    const int b_l = lane & 15, jjq = lane >> 4;

    const int nt4 = gwave >> 1, mt4 = gwave & 1;
    const int n0d = nt4*16, m0d = mt4*16;
    const int bbd = m0d + b_l;
    const int jd = nt4*4 + jjq;
    float cdec = cfin[(jd&1)*16384 + bbd*512 + (jd>>1)];

    for (int t = 0; t < 63; ++t) {
        // P2: attention -> s_tilde (blocks 0-31; their sentSt transitively proves h[t] visible)
        if (bid < 32) {
            if (t > 0) wait_flags(sentH + t*64, 64);
            const int bbb = bid;
            float* hsh = SH; float* red = SH + 1024; float* sc = SH + 1536;
            {
                u32 u = ((const u32*)Hd)[(size_t)t*16384 + bbb*512 + tid];
                hsh[2*tid]   = b2f_lo(u);
                hsh[2*tid+1] = b2f_hi(u);
            }
            __syncthreads();
            {
                int s = tid >> 3, p = tid & 7;
                const uint4* ep = (const uint4*)(encPB + (size_t)(s*32+bbb)*1024 + p*128);
                const float* hk = hsh + p*128;
                float a0=0,a1=0,a2=0,a3=0;
#pragma unroll 4
                for (int q8 = 0; q8 < 16; ++q8) {
                    uint4 u = ep[q8];
                    a0 += b2f_lo(u.x)*hk[q8*8+0] + b2f_hi(u.x)*hk[q8*8+1];
                    a1 += b2f_lo(u.y)*hk[q8*8+2] + b2f_hi(u.y)*hk[q8*8+3];
                    a2 += b2f_lo(u.z)*hk[q8*8+4] + b2f_hi(u.z)*hk[q8*8+5];
                    a3 += b2f_lo(u.w)*hk[q8*8+6] + b2f_hi(u.w)*hk[q8*8+7];
                }
                red[tid] = (a0+a1)+(a2+a3);
            }
            __syncthreads();
            if (tid < 64) {
                float v = 0;
#pragma unroll
                for (int pp = 0; pp < 8; ++pp) v += red[tid*8+pp];
                float m = v;
                for (int off = 32; off; off >>= 1) m = fmaxf(m, __shfl_xor(m, off));
                float e = expf(v - m);
                float ss = e;
                for (int off = 32; off; off >>= 1) ss += __shfl_xor(ss, off);
                sc[tid] = e / ss;
            }
            __syncthreads();
            {
                float st0 = 0, st1 = 0;
                const u32* eb = (const u32*)encBX + 16384 + bbb*512 + tid;
#pragma unroll 4
                for (int s2 = 0; s2 < 64; ++s2) {
                    u32 u = eb[(size_t)s2*16384];
                    float w = sc[s2];
                    st0 += w*b2f_lo(u); st1 += w*b2f_hi(u);
                }
                u32 pk = (u32)f2b(st0) | ((u32)f2b(st1) << 16);
                st_wt_u32((u32*)Stb + (size_t)t*16384 + bbb*512 + tid, pk);
            }
            __syncthreads();
            if (tid == 0) st_wt_u32(sentSt + t*64 + bid, 1u);
        }

        // P3: c_t = tanh([s_tilde, h] @ awo^T); single wait (sentSt implies h visible)
        wait_flags(sentSt + t*64, 32);
        {
            const int nt3 = bid;
            const int mt3 = wv >> 2, kq = wv & 3;
            const int m0 = mt3*16, n0 = nt3*16;
            const u16* Br = awoB + (size_t)(n0+lr)*2048 + kq*512 + lk8;
            const u16* As  = Stb + (size_t)t*32768 + (size_t)(m0+lr)*1024 + kq*512 + lk8;
            const u16* Ah2 = Hd  + (size_t)t*32768 + (size_t)(m0+lr)*1024 + (kq-2)*512 + lk8;
            const u16* Ar = (kq < 2) ? As : Ah2;
            f32x4 acc = {0.f,0.f,0.f,0.f};
#pragma unroll 4
            for (int i = 0; i < 16; ++i) {
                short8 av = *(const short8*)(Ar + i*32);
                short8 bv = *(const short8*)(Br + i*32);
                acc = __builtin_amdgcn_mfma_f32_16x16x32_bf16(av, bv, acc, 0, 0, 0);
            }
            float* PH = SH + wv*256;
#pragma unroll
            for (int r = 0; r < 4; ++r) PH[lane*4 + r] = acc[r];
            __syncthreads();
            if (kq == 0) {
#pragma unroll
                for (int r = 0; r < 4; ++r) {
                    float sum = SH[wv*256 + lane*4 + r] + SH[(wv+1)*256 + lane*4 + r]
                              + SH[(wv+2)*256 + lane*4 + r] + SH[(wv+3)*256 + lane*4 + r];
                    int bq = m0 + (lane>>4)*4 + r;
                    st_wt_u16(Ctb + (size_t)t*32768 + (size_t)bq*1024 + n0 + (lane&15),
                              f2b(tanhf(sum)));
                }
            }
            __syncthreads();
            if (tid == 0) st_wt_u32(sentCt + t*64 + bid, 1u);
        }

        // P4: gates = [c_t, h] @ Wdec^T + Xe; cell update
        wait_flags(sentCt + t*64, 64);
        {
            const u16* Br  = WdecB + (size_t)(n0d+lr)*2048 + lk8;
            const u16* Ac  = Ctb + (size_t)t*32768 + (size_t)(m0d+lr)*1024 + lk8;
            const u16* Ah3 = Hd  + (size_t)t*32768 + (size_t)(m0d+lr)*1024 + lk8;
            f32x4 acc = {0.f,0.f,0.f,0.f};
#pragma unroll 4
            for (int i = 0; i < 32; ++i) {
                short8 av = *(const short8*)(Ac + i*32);
                short8 bv = *(const short8*)(Br + i*32);
                acc = __builtin_amdgcn_mfma_f32_16x16x32_bf16(av, bv, acc, 0, 0, 0);
            }
#pragma unroll 4
            for (int i = 0; i < 32; ++i) {
                short8 av = *(const short8*)(Ah3 + i*32);
                short8 bv = *(const short8*)(Br + 1024 + i*32);
                acc = __builtin_amdgcn_mfma_f32_16x16x32_bf16(av, bv, acc, 0, 0, 0);
            }
            float* T = SH + wv*272;
            {
                const int rb = (lane>>4)*4;
#pragma unroll
                for (int r = 0; r < 4; ++r) T[(rb+r)*17 + (lane&15)] = acc[r];
            }
            __builtin_amdgcn_sched_barrier(0);
            ushort4 xr = *(const ushort4*)(Xe + (size_t)(t*32+bbd)*4096 + n0d + jjq*4);
            float gi = T[b_l*17 + jjq*4 + 0] + us2f(xr.x);
            float gf = T[b_l*17 + jjq*4 + 1] + us2f(xr.y);
            float gg = T[b_l*17 + jjq*4 + 2] + us2f(xr.z);
            float go = T[b_l*17 + jjq*4 + 3] + us2f(xr.w);
            float c2 = sigf(gf)*cdec + sigf(gi)*tanhf(gg);
            float h2 = sigf(go)*tanhf(c2);
            cdec = c2;
            st_wt_u16(Hd + (size_t)(t+1)*32768 + (size_t)bbd*1024 + jd, f2b(h2));
            __syncthreads();
            if (tid == 0) st_wt_u32(sentH + (t+1)*64 + bid, 1u);
        }
    }
}

// ---------------- generator GEMM ----------------
__global__ __launch_bounds__(256) void k_gemm_gen(const short* __restrict__ A,
                                                  const short* __restrict__ B,
                                                  const float* __restrict__ genb,
                                                  float* __restrict__ out) {
    int wave = threadIdx.x >> 6;
    int lane = threadIdx.x & 63;
    int tile = blockIdx.x * 4 + wave;
    int mt = tile & 31;
    int nt = tile >> 5;
    int m0 = mt*64, n0 = nt*64;
    int lr = lane & 15;
    int lk = (lane >> 4)*8;
    f32x4 acc[4][4] = {};
    for (int k0 = 0; k0 < 1024; k0 += 32) {
        short8 a[4], bfr[4];
#pragma unroll
        for (int mi = 0; mi < 4; ++mi)
            a[mi] = *(const short8*)(A + (long)(m0 + mi*16 + lr)*1024 + k0 + lk);
#pragma unroll
        for (int ni = 0; ni < 4; ++ni)
            bfr[ni] = *(const short8*)(B + (long)(n0 + ni*16 + lr)*1024 + k0 + lk);
#pragma unroll
        for (int mi = 0; mi < 4; ++mi)
#pragma unroll
            for (int ni = 0; ni < 4; ++ni)
                acc[mi][ni] = __builtin_amdgcn_mfma_f32_16x16x32_bf16(a[mi], bfr[ni], acc[mi][ni], 0, 0, 0);
    }
    int dcol = lane & 15;
    int drow = (lane >> 4)*4;
#pragma unroll
    for (int mi = 0; mi < 4; ++mi) {
        int mbase = m0 + mi*16 + drow;
#pragma unroll
        for (int ni = 0; ni < 4; ++ni) {
            int n = n0 + ni*16 + dcol;
            float bv = genb[n];
            f32x4 v = acc[mi][ni];
#pragma unroll
            for (int r = 0; r < 4; ++r) {
                int m = mbase + r;
                if (m < 2016) out[(long)(m + 32)*32000 + n] = v[r] + bv;
            }
        }
    }
}

// ---------------- log-softmax ----------------
__global__ __launch_bounds__(256) void k_lsm(float* __restrict__ out) {
    long row = 32 + blockIdx.x;
    float* p = out + row*32000L;
    float4* p4 = (float4*)p;
    int tid = threadIdx.x;
    __shared__ float sm[4];
    __shared__ float ss[4];
    float m = -1e30f;
    for (int i = tid; i < 8000; i += 256) {
        float4 v = p4[i];
        m = fmaxf(m, fmaxf(fmaxf(v.x, v.y), fmaxf(v.z, v.w)));
    }
    for (int off = 32; off; off >>= 1) m = fmaxf(m, __shfl_xor(m, off));
    if ((tid & 63) == 0) sm[tid >> 6] = m;
    __syncthreads();
    m = fmaxf(fmaxf(sm[0], sm[1]), fmaxf(sm[2], sm[3]));
    float s = 0;
    for (int i = tid; i < 8000; i += 256) {
        float4 v = p4[i];
        s += expf(v.x - m) + expf(v.y - m) + expf(v.z - m) + expf(v.w - m);
    }
    for (int off = 32; off; off >>= 1) s += __shfl_xor(s, off);
    if ((tid & 63) == 0) ss[tid >> 6] = s;
    __syncthreads();
    s = ss[0] + ss[1] + ss[2] + ss[3];
    float lse = m + logf(s);
    for (int i = tid; i < 8000; i += 256) {
        float4 v = p4[i];
        v.x -= lse; v.y -= lse; v.z -= lse; v.w -= lse;
        p4[i] = v;
    }
}

// ---------------- launch ----------------

extern "C" void kernel_launch(void* const* d_in, const int* in_sizes, int n_in,
                              void* d_out, int out_size, void* d_ws, size_t ws_size,
                              hipStream_t stream) {
    const float* eemb  = (const float*)d_in[0];
    const float* ewihf = (const float*)d_in[1];
    const float* ewhhf = (const float*)d_in[2];
    const float* ebf   = (const float*)d_in[3];
    const float* ewihb = (const float*)d_in[4];
    const float* ewhhb = (const float*)d_in[5];
    const float* ebb   = (const float*)d_in[6];
    const float* awi   = (const float*)d_in[7];
    const float* awo   = (const float*)d_in[8];
    const float* dwih  = (const float*)d_in[9];
    const float* dwhh  = (const float*)d_in[10];
    const float* db    = (const float*)d_in[11];
    const float* demb  = (const float*)d_in[12];
    const float* genw  = (const float*)d_in[13];
    const float* genb  = (const float*)d_in[14];
    const int* srci    = (const int*)d_in[15];
    const int* trgi    = (const int*)d_in[16];
    float* out = (float*)d_out;

    float* F = (float*)d_ws;
    u32* S       = (u32*)F;
    u32* sentE   = S;                      // 64 x 64
    u32* sentSt  = S + 4096;               // 63 x 64
    u32* sentCt  = S + 8192;               // 63 x 64
    u32* sentH   = S + 12288;              // 64 x 64
    float* cfin  = F + 16384;              // 32768 floats
    u16*   U     = (u16*)(F + 49152);

    u16* Xf_    = U;                       // 2048x2048
    u16* Xb_    = U + 4194304u;            // 2048x2048
    u16* Xe_    = U + 8388608u;            // 2016x4096
    u16* WencB  = U + 16646144u;           // 2 x 2048x512
    u16* awiTB  = U + 18743296u;           // 1024x1024
    u16* awoB   = U + 19791872u;           // 1024x2048
    u16* WdecB  = U + 21889024u;           // 4096x2048
    u16* genw_b = U + 30277632u;           // 32000x1024
    u16* encBX  = U + 63045632u;           // 65 x 32x1024
    u16* Hd     = U + 65175552u;           // 65 x 32x1024
    u16* Stb    = U + 67305472u;           // 63 x 32x1024
    u16* Ctb    = U + 69369856u;           // 63 x 32x1024
    u16* encPB  = U + 71434240u;           // 2048x1024

    k_zero<<<64, 256, 0, stream>>>(F, 16384);
    k_zero<<<64, 256, 0, stream>>>((float*)encBX, 16384);
    k_zero<<<2048, 256, 0, stream>>>(out, 1024000L);

    k_xw<<<dim3(32, 64), 256, 0, stream>>>(eemb, srci, ewihf, 300, 0, ebf, Xf_, 2048, 511, 9);
    k_xw<<<dim3(32, 64), 256, 0, stream>>>(eemb, srci, ewihb, 300, 0, ebb, Xb_, 2048, 511, 9);
    k_xw<<<dim3(64, 63), 256, 0, stream>>>(demb, trgi, dwih, 1324, 1024, db, Xe_, 4096, 1023, 10);

    k_wenc<<<4096, 256, 0, stream>>>(ewhhf, WencB);
    k_wenc<<<4096, 256, 0, stream>>>(ewhhb, WencB + 1048576u);
    k_awiT<<<4096, 256, 0, stream>>>(awi, awiTB);
    k_f2b<<<2048, 256, 0, stream>>>((const float4*)awo, (ushort4*)awoB, 524288L);
    k_wdec<<<8192, 256, 0, stream>>>(dwih, dwhh, WdecB);
    k_f2b<<<8192, 256, 0, stream>>>((const float4*)genw, (ushort4*)genw_b, 8192000L);

    k_enc<<<256, 512, 0, stream>>>(Xf_, Xb_, WencB, encBX, cfin, sentE);
    k_pack<<<64, 256, 0, stream>>>(encBX, Hd);
    k_mid<<<512, 256, 0, stream>>>(encBX, awiTB, encPB);
    k_dec<<<256, 512, 0, stream>>>(Xe_, awoB, WdecB, encBX, encPB,
                                   Hd, Stb, Ctb, cfin, sentSt, sentCt, sentH);

    k_gemm_gen<<<4000, 256, 0, stream>>>((const short*)(Hd + 32768u), (const short*)genw_b, genb, out);
    k_lsm<<<2016, 256, 0, stream>>>(out);
}

// Round 8
// 4999.718 us; speedup vs baseline: 1.0598x; 1.0314x over previous
//
#include <hip/hip_runtime.h>

typedef __attribute__((ext_vector_type(8))) short short8;
typedef __attribute__((ext_vector_type(4))) float f32x4;
typedef unsigned short u16;
typedef unsigned int u32;

static __device__ __forceinline__ float sigf(float x){ return 1.0f/(1.0f+expf(-x)); }

static __device__ __forceinline__ u16 f2b(float f){
    u32 u = __float_as_uint(f);
    u += 0x7FFFu + ((u>>16)&1u);   // RNE
    return (u16)(u>>16);
}
static __device__ __forceinline__ float us2f(u16 s){ return __uint_as_float(((u32)s)<<16); }
static __device__ __forceinline__ float b2f_lo(u32 u){ return __uint_as_float(u<<16); }
static __device__ __forceinline__ float b2f_hi(u32 u){ return __uint_as_float(u & 0xffff0000u); }

// Device-scope write-through stores (sc1): bypass L2, land at device-coherent point.
static __device__ __forceinline__ void st_wt_u16(u16* p, u16 v) {
    asm volatile("global_store_short %0, %1, off sc1" :: "v"(p), "v"((u32)v) : "memory");
}
static __device__ __forceinline__ void st_wt_u32(u32* p, u32 v) {
    asm volatile("global_store_dword %0, %1, off sc1" :: "v"(p), "v"(v) : "memory");
}
// Coherent (bypass L1+L2) load for sentinel polling.
static __device__ __forceinline__ u32 ld_cv(const u32* p){
    u32 v;
    asm volatile("global_load_dword %0, %1, off sc0 sc1\ns_waitcnt vmcnt(0)"
                 : "=v"(v) : "v"(p) : "memory");
    return v;
}

static __device__ __forceinline__ void hot_spin() {
    float x = 1.0f;
#pragma unroll
    for (int i = 0; i < 16; ++i) x = __builtin_fmaf(x, 1.0000001f, 1.0e-7f);
    asm volatile("" :: "v"(x));
}

// Monotonic per-block sentinels, ONE 128-B CACHE LINE PER WRITER (stride 32 u32).
// r2-r7 all packed 64 flags into 1-2 lines -> 32-64 writers serialize line
// ownership at ~0.25us each = the measured 15-19us/phase. This spreads them.
static __device__ __forceinline__ void wait_ge(const u32* base, int n, u32 tgt) {
    if ((int)threadIdx.x < n) {
        const u32* p = base + (size_t)threadIdx.x*32;
        while (ld_cv(p) < tgt) hot_spin();
    }
    __syncthreads();
}

// ---------------- utility / conversion kernels ----------------

__global__ __launch_bounds__(256) void k_zero(float* __restrict__ p, long n) {
    for (long i = (long)blockIdx.x*256 + threadIdx.x; i < n; i += (long)gridDim.x*256) p[i] = 0.0f;
}

__global__ __launch_bounds__(256) void k_f2b(const float4* __restrict__ src,
                                             ushort4* __restrict__ dst, long n4) {
    for (long i = (long)blockIdx.x*256 + threadIdx.x; i < n4; i += (long)gridDim.x*256) {
        float4 v = src[i];
        ushort4 u;
        u.x = f2b(v.x); u.y = f2b(v.y); u.z = f2b(v.z); u.w = f2b(v.w);
        dst[i] = u;
    }
}

__global__ __launch_bounds__(256) void k_wenc(const float* __restrict__ whh, u16* __restrict__ dst) {
    int i = blockIdx.x*256 + threadIdx.x;           // 1,048,576
    int n = i >> 9, k = i & 511;
    int j = n >> 2, q = n & 3;
    dst[i] = f2b(whh[(size_t)(q*512 + j)*512 + k]);
}

__global__ __launch_bounds__(256) void k_awiT(const float* __restrict__ awi, u16* __restrict__ dst) {
    int i = blockIdx.x*256 + threadIdx.x;           // 1,048,576
    int kcol = i >> 10, n = i & 1023;
    dst[i] = f2b(awi[(size_t)n*1024 + kcol]);
}

__global__ __launch_bounds__(256) void k_wdec(const float* __restrict__ dwih,
                                              const float* __restrict__ dwhh,
                                              u16* __restrict__ dst) {
    for (long i = (long)blockIdx.x*256 + threadIdx.x; i < 8388608L; i += (long)gridDim.x*256) {
        int n = (int)(i >> 11), k = (int)(i & 2047);
        int j = n >> 2, q = n & 3;
        float v = (k < 1024) ? dwih[(size_t)(q*1024 + j)*1324 + k]
                             : dwhh[(size_t)(q*1024 + j)*1024 + (k - 1024)];
        dst[i] = f2b(v);
    }
}

__global__ __launch_bounds__(256) void k_xw(const float* __restrict__ table,
                                            const int* __restrict__ idx,
                                            const float* __restrict__ W,
                                            int wstride, int koff,
                                            const float* __restrict__ bias,
                                            u16* __restrict__ outU, int N,
                                            int jmask, int jshift) {
    __shared__ float Xs[32][300];
    int m0 = blockIdx.y * 32;
    int j0 = blockIdx.x * 64;
    for (int i = threadIdx.x; i < 32*300; i += 256) {
        int r = i/300, c = i - r*300;
        Xs[r][c] = table[(size_t)idx[m0+r]*300 + c];
    }
    __syncthreads();
    int tx = threadIdx.x & 63, ty = threadIdx.x >> 6;
    int jj = j0 + tx;
    const float* wr = W + (size_t)jj*wstride + koff;
    float acc[8] = {0,0,0,0,0,0,0,0};
    for (int k = 0; k < 300; ++k) {
        float w = wr[k];
#pragma unroll
        for (int mi = 0; mi < 8; ++mi) acc[mi] += Xs[ty*8+mi][k] * w;
    }
    float bv = bias[jj];
    int col = ((jj & jmask) << 2) | (jj >> jshift);
#pragma unroll
    for (int mi = 0; mi < 8; ++mi)
        outU[(size_t)(m0 + ty*8 + mi)*N + col] = f2b(acc[mi] + bv);
}

// ---------------- encoder ----------------
__global__ __launch_bounds__(512) void k_enc(
    const u16* __restrict__ Xf, const u16* __restrict__ Xb,
    const u16* __restrict__ WencB,
    u16* __restrict__ encBX, float* __restrict__ cfin,
    u32* __restrict__ sentE)
{
    __shared__ float SH[2304];
    const int tid = threadIdx.x;
    const int bid = blockIdx.x;

    const int wv = tid >> 6, lane = tid & 63;
    const int gwave = bid*8 + wv;
    const int lr = lane & 15, lk8 = (lane >> 4)*8;
    const int b_l = lane & 15, jjq = lane >> 4;
    const int g0 = bid & 48;

    const int dir = gwave >> 8;
    const int mt = (gwave >> 7) & 1;
    const int nt = gwave & 127;
    const int m0 = mt*16, n0 = nt*16;
    const u16* Bw = WencB + (size_t)dir*1048576 + (size_t)(n0+lr)*512 + lk8;
    const u16* Xd = dir ? Xb : Xf;
    float* T = SH + wv*272;
    const int bb = m0 + b_l;
    const int j = nt*4 + jjq;
    float creg = 0.f;
    for (int t = 0; t < 64; ++t) {
        if (t > 0) wait_ge(sentE + (size_t)g0*32, 16, (u32)t);
        const int rslot = (t==0) ? 0 : (dir ? (65-t) : t);
        const u16* Ah = encBX + (size_t)rslot*32768 + (size_t)(m0+lr)*1024 + dir*512 + lk8;
        f32x4 acc = {0.f,0.f,0.f,0.f};
#pragma unroll
        for (int i = 0; i < 16; ++i) {
            short8 av = *(const short8*)(Ah + i*32);
            short8 bv = *(const short8*)(Bw + i*32);
            acc = __builtin_amdgcn_mfma_f32_16x16x32_bf16(av, bv, acc, 0, 0, 0);
        }
        {
            const int rb = (lane>>4)*4;
#pragma unroll
            for (int r = 0; r < 4; ++r) T[(rb+r)*17 + (lane&15)] = acc[r];
        }
        __builtin_amdgcn_sched_barrier(0);
        const int s = dir ? (63-t) : t;
        ushort4 xr = *(const ushort4*)(Xd + (size_t)(s*32+bb)*2048 + n0 + jjq*4);
        float gi = T[b_l*17 + jjq*4 + 0] + us2f(xr.x);
        float gf = T[b_l*17 + jjq*4 + 1] + us2f(xr.y);
        float gg = T[b_l*17 + jjq*4 + 2] + us2f(xr.z);
        float go = T[b_l*17 + jjq*4 + 3] + us2f(xr.w);
        float c2 = sigf(gf)*creg + sigf(gi)*tanhf(gg);
        float h2 = sigf(go)*tanhf(c2);
        creg = c2;
        st_wt_u16(encBX + (size_t)(s+1)*32768 + (size_t)bb*1024 + dir*512 + j, f2b(h2));
        __syncthreads();   // drains vmcnt: this block's h-writes are in LLC
        if (tid == 0) st_wt_u32(sentE + (size_t)bid*32, (u32)(t+1));
    }
    cfin[dir*16384 + bb*512 + j] = creg;
}

// ---------------- pack ----------------
__global__ __launch_bounds__(256) void k_pack(const u16* __restrict__ encBX,
                                              u16* __restrict__ Hd) {
    for (int gt = blockIdx.x*256 + threadIdx.x; gt < 32768; gt += 16384) {
        int b = gt >> 10, jj2 = gt & 1023;
        int d = jj2 & 1, k = jj2 >> 1;
        Hd[(size_t)b*1024 + jj2] = encBX[(size_t)(d ? 1 : 64)*32768 + (size_t)b*1024 + d*512 + k];
        Hd[(size_t)64*32768 + gt] = 0;
    }
}

// ---------------- encP GEMM ----------------
__global__ __launch_bounds__(256) void k_mid(const u16* __restrict__ encBX,
                                             const u16* __restrict__ awiTB,
                                             u16* __restrict__ encPB) {
    const int wv = threadIdx.x >> 6, lane = threadIdx.x & 63;
    const int lr = lane & 15, lk8 = (lane >> 4)*8;
    const u16* Abase = encBX + 32768;
#pragma unroll
    for (int ii = 0; ii < 4; ++ii) {
        int id = (blockIdx.x*4 + wv)*4 + ii;
        int mt2 = id >> 6, nt2 = id & 63;
        int m0 = mt2*16, n0 = nt2*16;
        const u16* Ar = Abase + (size_t)(m0+lr)*1024 + lk8;
        const u16* Br = awiTB + (size_t)(n0+lr)*1024 + lk8;
        f32x4 acc = {0.f,0.f,0.f,0.f};
#pragma unroll 8
        for (int i = 0; i < 32; ++i) {
            short8 av = *(const short8*)(Ar + i*32);
            short8 bv = *(const short8*)(Br + i*32);
            acc = __builtin_amdgcn_mfma_f32_16x16x32_bf16(av, bv, acc, 0, 0, 0);
        }
        int col = n0 + (lane&15);
        int rb = m0 + (lane>>4)*4;
#pragma unroll
        for (int r = 0; r < 4; ++r)
            encPB[(size_t)(rb+r)*1024 + col] = f2b(acc[r]);
    }
}

// ---------------- decoder ----------------
__global__ __launch_bounds__(512) void k_dec(
    const u16* __restrict__ Xe,
    const u16* __restrict__ awoB, const u16* __restrict__ WdecB,
    const u16* __restrict__ encBX, const u16* __restrict__ encPB,
    u16* __restrict__ Hd, u16* __restrict__ Stb, u16* __restrict__ Ctb,
    const float* __restrict__ cfin,
    u32* __restrict__ sentSt, u32* __restrict__ sentCt, u32* __restrict__ sentH)
{
    __shared__ float SH[2304];
    const int tid = threadIdx.x;
    const int bid = blockIdx.x;

    const int wv = tid >> 6, lane = tid & 63;
    const int gwave = bid*8 + wv;
    const int lr = lane & 15, lk8 = (lane >> 4)*8;
    const int b_l = lane & 15, jjq = lane >> 4;

    const int nt4 = gwave >> 1, mt4 = gwave & 1;
    const int n0d = nt4*16, m0d = mt4*16;
    const int bbd = m0d + b_l;
    const int jd = nt4*4 + jjq;
    float cdec = cfin[(jd&1)*16384 + bbd*512 + (jd>>1)];

    for (int t = 0; t < 63; ++t) {
        // P2: attention -> s_tilde (blocks 0-31)
        if (bid < 32) {
            if (t > 0) wait_ge(sentH, 64, (u32)t);
            const int bbb = bid;
            float* hsh = SH; float* red = SH + 1024; float* sc = SH + 1536;
            {
                u32 u = ((const u32*)Hd)[(size_t)t*16384 + bbb*512 + tid];
                hsh[2*tid]   = b2f_lo(u);
                hsh[2*tid+1] = b2f_hi(u);
            }
            __syncthreads();
            {
                int s = tid >> 3, p = tid & 7;
                const uint4* ep = (const uint4*)(encPB + (size_t)(s*32+bbb)*1024 + p*128);
                const float* hk = hsh + p*128;
                float a0=0,a1=0,a2=0,a3=0;
#pragma unroll 4
                for (int q8 = 0; q8 < 16; ++q8) {
                    uint4 u = ep[q8];
                    a0 += b2f_lo(u.x)*hk[q8*8+0] + b2f_hi(u.x)*hk[q8*8+1];
                    a1 += b2f_lo(u.y)*hk[q8*8+2] + b2f_hi(u.y)*hk[q8*8+3];
                    a2 += b2f_lo(u.z)*hk[q8*8+4] + b2f_hi(u.z)*hk[q8*8+5];
                    a3 += b2f_lo(u.w)*hk[q8*8+6] + b2f_hi(u.w)*hk[q8*8+7];
                }
                red[tid] = (a0+a1)+(a2+a3);
            }
            __syncthreads();
            if (tid < 64) {
                float v = 0;
#pragma unroll
                for (int pp = 0; pp < 8; ++pp) v += red[tid*8+pp];
                float m = v;
                for (int off = 32; off; off >>= 1) m = fmaxf(m, __shfl_xor(m, off));
                float e = expf(v - m);
                float ss = e;
                for (int off = 32; off; off >>= 1) ss += __shfl_xor(ss, off);
                sc[tid] = e / ss;
            }
            __syncthreads();
            {
                float st0 = 0, st1 = 0;
                const u32* eb = (const u32*)encBX + 16384 + bbb*512 + tid;
#pragma unroll 4
                for (int s2 = 0; s2 < 64; ++s2) {
                    u32 u = eb[(size_t)s2*16384];
                    float w = sc[s2];
                    st0 += w*b2f_lo(u); st1 += w*b2f_hi(u);
                }
                u32 pk = (u32)f2b(st0) | ((u32)f2b(st1) << 16);
                st_wt_u32((u32*)Stb + (size_t)t*16384 + bbb*512 + tid, pk);
            }
            __syncthreads();
            if (tid == 0) st_wt_u32(sentSt + (size_t)bid*32, (u32)(t+1));
        }

        // P3: c_t = tanh([s_tilde, h] @ awo^T); sentSt >= t+1 transitively proves h[t]
        wait_ge(sentSt, 32, (u32)(t+1));
        {
            const int nt3 = bid;
            const int mt3 = wv >> 2, kq = wv & 3;
            const int m0 = mt3*16, n0 = nt3*16;
            const u16* Br = awoB + (size_t)(n0+lr)*2048 + kq*512 + lk8;
            const u16* As  = Stb + (size_t)t*32768 + (size_t)(m0+lr)*1024 + kq*512 + lk8;
            const u16* Ah2 = Hd  + (size_t)t*32768 + (size_t)(m0+lr)*1024 + (kq-2)*512 + lk8;
            const u16* Ar = (kq < 2) ? As : Ah2;
            f32x4 acc = {0.f,0.f,0.f,0.f};
#pragma unroll 4
            for (int i = 0; i < 16; ++i) {
                short8 av = *(const short8*)(Ar + i*32);
                short8 bv = *(const short8*)(Br + i*32);
                acc = __builtin_amdgcn_mfma_f32_16x16x32_bf16(av, bv, acc, 0, 0, 0);
            }
            float* PH = SH + wv*256;
#pragma unroll
            for (int r = 0; r < 4; ++r) PH[lane*4 + r] = acc[r];
            __syncthreads();
            if (kq == 0) {
#pragma unroll
                for (int r = 0; r < 4; ++r) {
                    float sum = SH[wv*256 + lane*4 + r] + SH[(wv+1)*256 + lane*4 + r]
                              + SH[(wv+2)*256 + lane*4 + r] + SH[(wv+3)*256 + lane*4 + r];
                    int bq = m0 + (lane>>4)*4 + r;
                    st_wt_u16(Ctb + (size_t)t*32768 + (size_t)bq*1024 + n0 + (lane&15),
                              f2b(tanhf(sum)));
                }
            }
            __syncthreads();
            if (tid == 0) st_wt_u32(sentCt + (size_t)bid*32, (u32)(t+1));
        }

        // P4: gates = [c_t, h] @ Wdec^T + Xe; cell update
        wait_ge(sentCt, 64, (u32)(t+1));
        {
            const u16* Br  = WdecB + (size_t)(n0d+lr)*2048 + lk8;
            const u16* Ac  = Ctb + (size_t)t*32768 + (size_t)(m0d+lr)*1024 + lk8;
            const u16* Ah3 = Hd  + (size_t)t*32768 + (size_t)(m0d+lr)*1024 + lk8;
            f32x4 acc = {0.f,0.f,0.f,0.f};
#pragma unroll 4
            for (int i = 0; i < 32; ++i) {
                short8 av = *(const short8*)(Ac + i*32);
                short8 bv = *(const short8*)(Br + i*32);
                acc = __builtin_amdgcn_mfma_f32_16x16x32_bf16(av, bv, acc, 0, 0, 0);
            }
#pragma unroll 4
            for (int i = 0; i < 32; ++i) {
                short8 av = *(const short8*)(Ah3 + i*32);
                short8 bv = *(const short8*)(Br + 1024 + i*32);
                acc = __builtin_amdgcn_mfma_f32_16x16x32_bf16(av, bv, acc, 0, 0, 0);
            }
            float* T = SH + wv*272;
            {
                const int rb = (lane>>4)*4;
#pragma unroll
                for (int r = 0; r < 4; ++r) T[(rb+r)*17 + (lane&15)] = acc[r];
            }
            __builtin_amdgcn_sched_barrier(0);
            ushort4 xr = *(const ushort4*)(Xe + (size_t)(t*32+bbd)*4096 + n0d + jjq*4);
            float gi = T[b_l*17 + jjq*4 + 0] + us2f(xr.x);
            float gf = T[b_l*17 + jjq*4 + 1] + us2f(xr.y);
            float gg = T[b_l*17 + jjq*4 + 2] + us2f(xr.z);
            float go = T[b_l*17 + jjq*4 + 3] + us2f(xr.w);
            float c2 = sigf(gf)*cdec + sigf(gi)*tanhf(gg);
            float h2 = sigf(go)*tanhf(c2);
            cdec = c2;
            st_wt_u16(Hd + (size_t)(t+1)*32768 + (size_t)bbd*1024 + jd, f2b(h2));
            __syncthreads();
            if (tid == 0) st_wt_u32(sentH + (size_t)bid*32, (u32)(t+1));
        }
    }
}

// ---------------- generator GEMM ----------------
__global__ __launch_bounds__(256) void k_gemm_gen(const short* __restrict__ A,
                                                  const short* __restrict__ B,
                                                  const float* __restrict__ genb,
                                                  float* __restrict__ out) {
    int wave = threadIdx.x >> 6;
    int lane = threadIdx.x & 63;
    int tile = blockIdx.x * 4 + wave;
    int mt = tile & 31;
    int nt = tile >> 5;
    int m0 = mt*64, n0 = nt*64;
    int lr = lane & 15;
    int lk = (lane >> 4)*8;
    f32x4 acc[4][4] = {};
    for (int k0 = 0; k0 < 1024; k0 += 32) {
        short8 a[4], bfr[4];
#pragma unroll
        for (int mi = 0; mi < 4; ++mi)
            a[mi] = *(const short8*)(A + (long)(m0 + mi*16 + lr)*1024 + k0 + lk);
#pragma unroll
        for (int ni = 0; ni < 4; ++ni)
            bfr[ni] = *(const short8*)(B + (long)(n0 + ni*16 + lr)*1024 + k0 + lk);
#pragma unroll
        for (int mi = 0; mi < 4; ++mi)
#pragma unroll
            for (int ni = 0; ni < 4; ++ni)
                acc[mi][ni] = __builtin_amdgcn_mfma_f32_16x16x32_bf16(a[mi], bfr[ni], acc[mi][ni], 0, 0, 0);
    }
    int dcol = lane & 15;
    int drow = (lane >> 4)*4;
#pragma unroll
    for (int mi = 0; mi < 4; ++mi) {
        int mbase = m0 + mi*16 + drow;
#pragma unroll
        for (int ni = 0; ni < 4; ++ni) {
            int n = n0 + ni*16 + dcol;
            float bv = genb[n];
            f32x4 v = acc[mi][ni];
#pragma unroll
            for (int r = 0; r < 4; ++r) {
                int m = mbase + r;
                if (m < 2016) out[(long)(m + 32)*32000 + n] = v[r] + bv;
            }
        }
    }
}

// ---------------- log-softmax ----------------
__global__ __launch_bounds__(256) void k_lsm(float* __restrict__ out) {
    long row = 32 + blockIdx.x;
    float* p = out + row*32000L;
    float4* p4 = (float4*)p;
    int tid = threadIdx.x;
    __shared__ float sm[4];
    __shared__ float ss[4];
    float m = -1e30f;
    for (int i = tid; i < 8000; i += 256) {
        float4 v = p4[i];
        m = fmaxf(m, fmaxf(fmaxf(v.x, v.y), fmaxf(v.z, v.w)));
    }
    for (int off = 32; off; off >>= 1) m = fmaxf(m, __shfl_xor(m, off));
    if ((tid & 63) == 0) sm[tid >> 6] = m;
    __syncthreads();
    m = fmaxf(fmaxf(sm[0], sm[1]), fmaxf(sm[2], sm[3]));
    float s = 0;
    for (int i = tid; i < 8000; i += 256) {
        float4 v = p4[i];
        s += expf(v.x - m) + expf(v.y - m) + expf(v.z - m) + expf(v.w - m);
    }
    for (int off = 32; off; off >>= 1) s += __shfl_xor(s, off);
    if ((tid & 63) == 0) ss[tid >> 6] = s;
    __syncthreads();
    s = ss[0] + ss[1] + ss[2] + ss[3];
    float lse = m + logf(s);
    for (int i = tid; i < 8000; i += 256) {
        float4 v = p4[i];
        v.x -= lse; v.y -= lse; v.z -= lse; v.w -= lse;
        p4[i] = v;
    }
}

// ---------------- launch ----------------

extern "C" void kernel_launch(void* const* d_in, const int* in_sizes, int n_in,
                              void* d_out, int out_size, void* d_ws, size_t ws_size,
                              hipStream_t stream) {
    const float* eemb  = (const float*)d_in[0];
    const float* ewihf = (const float*)d_in[1];
    const float* ewhhf = (const float*)d_in[2];
    const float* ebf   = (const float*)d_in[3];
    const float* ewihb = (const float*)d_in[4];
    const float* ewhhb = (const float*)d_in[5];
    const float* ebb   = (const float*)d_in[6];
    const float* awi   = (const float*)d_in[7];
    const float* awo   = (const float*)d_in[8];
    const float* dwih  = (const float*)d_in[9];
    const float* dwhh  = (const float*)d_in[10];
    const float* db    = (const float*)d_in[11];
    const float* demb  = (const float*)d_in[12];
    const float* genw  = (const float*)d_in[13];
    const float* genb  = (const float*)d_in[14];
    const int* srci    = (const int*)d_in[15];
    const int* trgi    = (const int*)d_in[16];
    float* out = (float*)d_out;

    float* F = (float*)d_ws;
    u32* S       = (u32*)F;
    u32* sentE   = S;                      // 64 blocks x 32 u32 (1 line each)
    u32* sentSt  = S + 2048;               // 64 x 32
    u32* sentCt  = S + 4096;               // 64 x 32
    u32* sentH   = S + 6144;               // 64 x 32
    float* cfin  = F + 8192;               // 32768 floats
    u16*   U     = (u16*)(F + 40960);

    u16* Xf_    = U;                       // 2048x2048
    u16* Xb_    = U + 4194304u;            // 2048x2048
    u16* Xe_    = U + 8388608u;            // 2016x4096
    u16* WencB  = U + 16646144u;           // 2 x 2048x512
    u16* awiTB  = U + 18743296u;           // 1024x1024
    u16* awoB   = U + 19791872u;           // 1024x2048
    u16* WdecB  = U + 21889024u;           // 4096x2048
    u16* genw_b = U + 30277632u;           // 32000x1024
    u16* encBX  = U + 63045632u;           // 65 x 32x1024
    u16* Hd     = U + 65175552u;           // 65 x 32x1024
    u16* Stb    = U + 67305472u;           // 63 x 32x1024
    u16* Ctb    = U + 69369856u;           // 63 x 32x1024
    u16* encPB  = U + 71434240u;           // 2048x1024

    k_zero<<<32, 256, 0, stream>>>(F, 8192);           // sentinel lines
    k_zero<<<64, 256, 0, stream>>>((float*)encBX, 16384);
    k_zero<<<2048, 256, 0, stream>>>(out, 1024000L);

    k_xw<<<dim3(32, 64), 256, 0, stream>>>(eemb, srci, ewihf, 300, 0, ebf, Xf_, 2048, 511, 9);
    k_xw<<<dim3(32, 64), 256, 0, stream>>>(eemb, srci, ewihb, 300, 0, ebb, Xb_, 2048, 511, 9);
    k_xw<<<dim3(64, 63), 256, 0, stream>>>(demb, trgi, dwih, 1324, 1024, db, Xe_, 4096, 1023, 10);

    k_wenc<<<4096, 256, 0, stream>>>(ewhhf, WencB);
    k_wenc<<<4096, 256, 0, stream>>>(ewhhb, WencB + 1048576u);
    k_awiT<<<4096, 256, 0, stream>>>(awi, awiTB);
    k_f2b<<<2048, 256, 0, stream>>>((const float4*)awo, (ushort4*)awoB, 524288L);
    k_wdec<<<8192, 256, 0, stream>>>(dwih, dwhh, WdecB);
    k_f2b<<<8192, 256, 0, stream>>>((const float4*)genw, (ushort4*)genw_b, 8192000L);

    k_enc<<<64, 512, 0, stream>>>(Xf_, Xb_, WencB, encBX, cfin, sentE);
    k_pack<<<64, 256, 0, stream>>>(encBX, Hd);
    k_mid<<<512, 256, 0, stream>>>(encBX, awiTB, encPB);
    k_dec<<<64, 512, 0, stream>>>(Xe_, awoB, WdecB, encBX, encPB,
                                  Hd, Stb, Ctb, cfin, sentSt, sentCt, sentH);

    k_gemm_gen<<<4000, 256, 0, stream>>>((const short*)(Hd + 32768u), (const short*)genw_b, genb, out);
    k_lsm<<<2016, 256, 0, stream>>>(out);
}

// Round 9
// 3460.826 us; speedup vs baseline: 1.5310x; 1.4447x over previous
//
#include <hip/hip_runtime.h>

typedef __attribute__((ext_vector_type(8))) short short8;
typedef __attribute__((ext_vector_type(4))) float f32x4;
typedef unsigned short u16;
typedef unsigned int u32;

static __device__ __forceinline__ float sigf(float x){ return 1.0f/(1.0f+expf(-x)); }

static __device__ __forceinline__ u16 f2b(float f){
    u32 u = __float_as_uint(f);
    u += 0x7FFFu + ((u>>16)&1u);   // RNE
    return (u16)(u>>16);
}
static __device__ __forceinline__ float us2f(u16 s){ return __uint_as_float(((u32)s)<<16); }
static __device__ __forceinline__ float b2f_lo(u32 u){ return __uint_as_float(u<<16); }
static __device__ __forceinline__ float b2f_hi(u32 u){ return __uint_as_float(u & 0xffff0000u); }

static __device__ __forceinline__ void st_wt_u16(u16* p, u16 v) {
    asm volatile("global_store_short %0, %1, off sc1" :: "v"(p), "v"((u32)v) : "memory");
}
static __device__ __forceinline__ void st_wt_u32(u32* p, u32 v) {
    asm volatile("global_store_dword %0, %1, off sc1" :: "v"(p), "v"(v) : "memory");
}
static __device__ __forceinline__ u32 ld_cv(const u32* p){
    u32 v;
    asm volatile("global_load_dword %0, %1, off sc0 sc1\ns_waitcnt vmcnt(0)"
                 : "=v"(v) : "v"(p) : "memory");
    return v;
}

static __device__ __forceinline__ void hot_spin() {
    float x = 1.0f;
#pragma unroll
    for (int i = 0; i < 16; ++i) x = __builtin_fmaf(x, 1.0000001f, 1.0e-7f);
    asm volatile("" :: "v"(x));
}

// Monotonic per-block sentinels, one 128B line per writer (stride 32 u32).
static __device__ __forceinline__ void wait_ge(const u32* base, int n, u32 tgt) {
    if ((int)threadIdx.x < n) {
        const u32* p = base + (size_t)threadIdx.x*32;
        while (ld_cv(p) < tgt) hot_spin();
    }
    __syncthreads();
}

// ---------------- utility / conversion kernels ----------------

__global__ __launch_bounds__(256) void k_zero(float* __restrict__ p, long n) {
    for (long i = (long)blockIdx.x*256 + threadIdx.x; i < n; i += (long)gridDim.x*256) p[i] = 0.0f;
}

__global__ __launch_bounds__(256) void k_f2b(const float4* __restrict__ src,
                                             ushort4* __restrict__ dst, long n4) {
    for (long i = (long)blockIdx.x*256 + threadIdx.x; i < n4; i += (long)gridDim.x*256) {
        float4 v = src[i];
        ushort4 u;
        u.x = f2b(v.x); u.y = f2b(v.y); u.z = f2b(v.z); u.w = f2b(v.w);
        dst[i] = u;
    }
}

__global__ __launch_bounds__(256) void k_wenc(const float* __restrict__ whh, u16* __restrict__ dst) {
    int i = blockIdx.x*256 + threadIdx.x;           // 1,048,576
    int n = i >> 9, k = i & 511;
    int j = n >> 2, q = n & 3;
    dst[i] = f2b(whh[(size_t)(q*512 + j)*512 + k]);
}

__global__ __launch_bounds__(256) void k_awiT(const float* __restrict__ awi, u16* __restrict__ dst) {
    int i = blockIdx.x*256 + threadIdx.x;           // 1,048,576
    int kcol = i >> 10, n = i & 1023;
    dst[i] = f2b(awi[(size_t)n*1024 + kcol]);
}

__global__ __launch_bounds__(256) void k_wdec(const float* __restrict__ dwih,
                                              const float* __restrict__ dwhh,
                                              u16* __restrict__ dst) {
    for (long i = (long)blockIdx.x*256 + threadIdx.x; i < 8388608L; i += (long)gridDim.x*256) {
        int n = (int)(i >> 11), k = (int)(i & 2047);
        int j = n >> 2, q = n & 3;
        float v = (k < 1024) ? dwih[(size_t)(q*1024 + j)*1324 + k]
                             : dwhh[(size_t)(q*1024 + j)*1024 + (k - 1024)];
        dst[i] = f2b(v);
    }
}

__global__ __launch_bounds__(256) void k_xw(const float* __restrict__ table,
                                            const int* __restrict__ idx,
                                            const float* __restrict__ W,
                                            int wstride, int koff,
                                            const float* __restrict__ bias,
                                            u16* __restrict__ outU, int N,
                                            int jmask, int jshift) {
    __shared__ float Xs[32][300];
    int m0 = blockIdx.y * 32;
    int j0 = blockIdx.x * 64;
    for (int i = threadIdx.x; i < 32*300; i += 256) {
        int r = i/300, c = i - r*300;
        Xs[r][c] = table[(size_t)idx[m0+r]*300 + c];
    }
    __syncthreads();
    int tx = threadIdx.x & 63, ty = threadIdx.x >> 6;
    int jj = j0 + tx;
    const float* wr = W + (size_t)jj*wstride + koff;
    float acc[8] = {0,0,0,0,0,0,0,0};
    for (int k = 0; k < 300; ++k) {
        float w = wr[k];
#pragma unroll
        for (int mi = 0; mi < 8; ++mi) acc[mi] += Xs[ty*8+mi][k] * w;
    }
    float bv = bias[jj];
    int col = ((jj & jmask) << 2) | (jj >> jshift);
#pragma unroll
    for (int mi = 0; mi < 8; ++mi)
        outU[(size_t)(m0 + ty*8 + mi)*N + col] = f2b(acc[mi] + bv);
}

// ---------------- encoder (64 blocks, weights pinned in VGPRs) ----------------
__global__ __launch_bounds__(512, 1) void k_enc(
    const u16* __restrict__ Xf, const u16* __restrict__ Xb,
    const u16* __restrict__ WencB,
    u16* __restrict__ encBX, float* __restrict__ cfin,
    u32* __restrict__ sentE)
{
    __shared__ float SH[2304];
    const int tid = threadIdx.x;
    const int bid = blockIdx.x;
    const int wv = tid >> 6, lane = tid & 63;
    const int gwave = bid*8 + wv;
    const int lr = lane & 15, lk8 = (lane >> 4)*8;
    const int b_l = lane & 15, jjq = lane >> 4;
    const int g0 = bid & 48;

    const int dir = gwave >> 8;
    const int mt = (gwave >> 7) & 1;
    const int nt = gwave & 127;
    const int m0 = mt*16, n0 = nt*16;
    const u16* Bw = WencB + (size_t)dir*1048576 + (size_t)(n0+lr)*512 + lk8;
    const u16* Xd = dir ? Xb : Xf;
    float* T = SH + wv*272;
    const int bb = m0 + b_l;
    const int j = nt*4 + jjq;

    // pin the recurrent weight slice: identical every step
    short8 bw[16];
#pragma unroll
    for (int i = 0; i < 16; ++i) bw[i] = *(const short8*)(Bw + i*32);

    float creg = 0.f;
    for (int t = 0; t < 64; ++t) {
        if (t > 0) wait_ge(sentE + (size_t)g0*32, 16, (u32)t);
        const int rslot = (t==0) ? 0 : (dir ? (65-t) : t);
        const u16* Ah = encBX + (size_t)rslot*32768 + (size_t)(m0+lr)*1024 + dir*512 + lk8;
        short8 av[16];
#pragma unroll
        for (int i = 0; i < 16; ++i) av[i] = *(const short8*)(Ah + i*32);
        f32x4 acc = {0.f,0.f,0.f,0.f};
#pragma unroll
        for (int i = 0; i < 16; ++i)
            acc = __builtin_amdgcn_mfma_f32_16x16x32_bf16(av[i], bw[i], acc, 0, 0, 0);
        {
            const int rb = (lane>>4)*4;
#pragma unroll
            for (int r = 0; r < 4; ++r) T[(rb+r)*17 + (lane&15)] = acc[r];
        }
        __builtin_amdgcn_sched_barrier(0);
        const int s = dir ? (63-t) : t;
        ushort4 xr = *(const ushort4*)(Xd + (size_t)(s*32+bb)*2048 + n0 + jjq*4);
        float gi = T[b_l*17 + jjq*4 + 0] + us2f(xr.x);
        float gf = T[b_l*17 + jjq*4 + 1] + us2f(xr.y);
        float gg = T[b_l*17 + jjq*4 + 2] + us2f(xr.z);
        float go = T[b_l*17 + jjq*4 + 3] + us2f(xr.w);
        float c2 = sigf(gf)*creg + sigf(gi)*tanhf(gg);
        float h2 = sigf(go)*tanhf(c2);
        creg = c2;
        st_wt_u16(encBX + (size_t)(s+1)*32768 + (size_t)bb*1024 + dir*512 + j, f2b(h2));
        __syncthreads();
        if (tid == 0) st_wt_u32(sentE + (size_t)bid*32, (u32)(t+1));
    }
    cfin[dir*16384 + bb*512 + j] = creg;
}

// ---------------- pack ----------------
__global__ __launch_bounds__(256) void k_pack(const u16* __restrict__ encBX,
                                              u16* __restrict__ Hd) {
    for (int gt = blockIdx.x*256 + threadIdx.x; gt < 32768; gt += 16384) {
        int b = gt >> 10, jj2 = gt & 1023;
        int d = jj2 & 1, k = jj2 >> 1;
        Hd[(size_t)b*1024 + jj2] = encBX[(size_t)(d ? 1 : 64)*32768 + (size_t)b*1024 + d*512 + k];
        Hd[(size_t)64*32768 + gt] = 0;
    }
}

// ---------------- encP GEMM ----------------
__global__ __launch_bounds__(256) void k_mid(const u16* __restrict__ encBX,
                                             const u16* __restrict__ awiTB,
                                             u16* __restrict__ encPB) {
    const int wv = threadIdx.x >> 6, lane = threadIdx.x & 63;
    const int lr = lane & 15, lk8 = (lane >> 4)*8;
    const u16* Abase = encBX + 32768;
#pragma unroll
    for (int ii = 0; ii < 4; ++ii) {
        int id = (blockIdx.x*4 + wv)*4 + ii;
        int mt2 = id >> 6, nt2 = id & 63;
        int m0 = mt2*16, n0 = nt2*16;
        const u16* Ar = Abase + (size_t)(m0+lr)*1024 + lk8;
        const u16* Br = awiTB + (size_t)(n0+lr)*1024 + lk8;
        f32x4 acc = {0.f,0.f,0.f,0.f};
#pragma unroll 8
        for (int i = 0; i < 32; ++i) {
            short8 av = *(const short8*)(Ar + i*32);
            short8 bv = *(const short8*)(Br + i*32);
            acc = __builtin_amdgcn_mfma_f32_16x16x32_bf16(av, bv, acc, 0, 0, 0);
        }
        int col = n0 + (lane&15);
        int rb = m0 + (lane>>4)*4;
#pragma unroll
        for (int r = 0; r < 4; ++r)
            encPB[(size_t)(rb+r)*1024 + col] = f2b(acc[r]);
    }
}

// ---------------- decoder (256 blocks, weights pinned in VGPRs) ----------------
// P2: blocks 0-31 (one per batch item). P3: blocks 32-95 (nt3 = bid-32).
// P4: all 256 blocks (nt = bid; 8 waves = 2 m-tiles x 4 K-slices, LDS reduce).
__global__ __launch_bounds__(512, 1) void k_dec(
    const u16* __restrict__ Xe,
    const u16* __restrict__ awoB, const u16* __restrict__ WdecB,
    const u16* __restrict__ encBX, const u16* __restrict__ encPB,
    u16* __restrict__ Hd, u16* __restrict__ Stb, u16* __restrict__ Ctb,
    const float* __restrict__ cfin,
    u32* __restrict__ sentSt, u32* __restrict__ sentCt, u32* __restrict__ sentH)
{
    __shared__ float SH[2592];
    const int tid = threadIdx.x;
    const int bid = blockIdx.x;
    const int wv = tid >> 6, lane = tid & 63;
    const int lr = lane & 15, lk8 = (lane >> 4)*8;
    const int b_l = lane & 15, jjq = lane >> 4;

    // P4 assignment
    const int mt4 = wv & 1, kq4 = wv >> 1;
    const int m0d = mt4*16;
    const int bbd = m0d + b_l;
    const int jd = bid*4 + jjq;
    float cdec = cfin[(jd&1)*16384 + bbd*512 + (jd>>1)];

    // pinned P4 weight slice (rows bid*16.., K-slice kq4)
    short8 wp[16];
#pragma unroll
    for (int i = 0; i < 16; ++i)
        wp[i] = *(const short8*)(WdecB + (size_t)(bid*16+lr)*2048 + kq4*512 + lk8 + i*32);

    // pinned P3 weight slice for mid blocks
    const bool midP3 = (bid >= 32 && bid < 96);
    const int nt3 = bid - 32;
    const int mt3 = wv & 1, kq3 = wv >> 1;
    short8 w3[16];
    if (midP3) {
#pragma unroll
        for (int i = 0; i < 16; ++i)
            w3[i] = *(const short8*)(awoB + (size_t)(nt3*16+lr)*2048 + kq3*512 + lk8 + i*32);
    }

    for (int t = 0; t < 63; ++t) {
        // ---- P2: attention -> s_tilde ----
        if (bid < 32) {
            if (t > 0) wait_ge(sentH, 256, (u32)t);
            const int bbb = bid;
            float* hsh = SH; float* red = SH + 1024; float* sc = SH + 1536;
            {
                u32 u = ((const u32*)Hd)[(size_t)t*16384 + bbb*512 + tid];
                hsh[2*tid]   = b2f_lo(u);
                hsh[2*tid+1] = b2f_hi(u);
            }
            __syncthreads();
            {
                int s = tid >> 3, p = tid & 7;
                const uint4* ep = (const uint4*)(encPB + (size_t)(s*32+bbb)*1024 + p*128);
                uint4 er[16];
#pragma unroll
                for (int q8 = 0; q8 < 16; ++q8) er[q8] = ep[q8];
                const float* hk = hsh + p*128;
                float a0=0,a1=0,a2=0,a3=0;
#pragma unroll
                for (int q8 = 0; q8 < 16; ++q8) {
                    uint4 u = er[q8];
                    a0 += b2f_lo(u.x)*hk[q8*8+0] + b2f_hi(u.x)*hk[q8*8+1];
                    a1 += b2f_lo(u.y)*hk[q8*8+2] + b2f_hi(u.y)*hk[q8*8+3];
                    a2 += b2f_lo(u.z)*hk[q8*8+4] + b2f_hi(u.z)*hk[q8*8+5];
                    a3 += b2f_lo(u.w)*hk[q8*8+6] + b2f_hi(u.w)*hk[q8*8+7];
                }
                red[tid] = (a0+a1)+(a2+a3);
            }
            __syncthreads();
            if (tid < 64) {
                float v = 0;
#pragma unroll
                for (int pp = 0; pp < 8; ++pp) v += red[tid*8+pp];
                float m = v;
                for (int off = 32; off; off >>= 1) m = fmaxf(m, __shfl_xor(m, off));
                float e = expf(v - m);
                float ss = e;
                for (int off = 32; off; off >>= 1) ss += __shfl_xor(ss, off);
                sc[tid] = e / ss;
            }
            __syncthreads();
            {
                const u32* eb = (const u32*)encBX + 16384 + bbb*512 + tid;
                u32 ebv[64];
#pragma unroll
                for (int s2 = 0; s2 < 64; ++s2) ebv[s2] = eb[(size_t)s2*16384];
                float st0 = 0, st1 = 0;
#pragma unroll
                for (int s2 = 0; s2 < 64; ++s2) {
                    float w = sc[s2];
                    st0 += w*b2f_lo(ebv[s2]); st1 += w*b2f_hi(ebv[s2]);
                }
                u32 pk = (u32)f2b(st0) | ((u32)f2b(st1) << 16);
                st_wt_u32((u32*)Stb + (size_t)t*16384 + bbb*512 + tid, pk);
            }
            __syncthreads();
            if (tid == 0) st_wt_u32(sentSt + (size_t)bid*32, (u32)(t+1));
        }

        // ---- P3: c_t = tanh([s_tilde, h] @ awo^T) ----
        if (midP3) {
            wait_ge(sentSt, 32, (u32)(t+1));   // transitively proves h[t] visible
            const u16* Ab = (kq3 < 2)
                ? (Stb + (size_t)t*32768 + (size_t)(mt3*16+lr)*1024 + kq3*512 + lk8)
                : (Hd  + (size_t)t*32768 + (size_t)(mt3*16+lr)*1024 + (kq3-2)*512 + lk8);
            short8 av[16];
#pragma unroll
            for (int i = 0; i < 16; ++i) av[i] = *(const short8*)(Ab + i*32);
            f32x4 acc = {0.f,0.f,0.f,0.f};
#pragma unroll
            for (int i = 0; i < 16; ++i)
                acc = __builtin_amdgcn_mfma_f32_16x16x32_bf16(av[i], w3[i], acc, 0, 0, 0);
#pragma unroll
            for (int r = 0; r < 4; ++r) SH[wv*256 + lane*4 + r] = acc[r];
            __syncthreads();
            if (wv < 2) {   // kq3==0 waves; mt3 = wv
#pragma unroll
                for (int r = 0; r < 4; ++r) {
                    float sum = SH[(wv+0)*256 + lane*4 + r] + SH[(wv+2)*256 + lane*4 + r]
                              + SH[(wv+4)*256 + lane*4 + r] + SH[(wv+6)*256 + lane*4 + r];
                    int bq = wv*16 + (lane>>4)*4 + r;
                    st_wt_u16(Ctb + (size_t)t*32768 + (size_t)bq*1024 + nt3*16 + (lane&15),
                              f2b(tanhf(sum)));
                }
            }
            __syncthreads();
            if (tid == 0) st_wt_u32(sentCt + (size_t)(bid-32)*32, (u32)(t+1));
        }

        // ---- P4: gates = [c_t, h] @ Wdec^T + Xe; cell update ----
        wait_ge(sentCt, 64, (u32)(t+1));   // transitively proves Stb/Hd visible
        {
            const u16* Ab = (kq4 < 2)
                ? (Ctb + (size_t)t*32768 + (size_t)(m0d+lr)*1024 + kq4*512 + lk8)
                : (Hd  + (size_t)t*32768 + (size_t)(m0d+lr)*1024 + (kq4-2)*512 + lk8);
            short8 av[16];
#pragma unroll
            for (int i = 0; i < 16; ++i) av[i] = *(const short8*)(Ab + i*32);
            f32x4 acc = {0.f,0.f,0.f,0.f};
#pragma unroll
            for (int i = 0; i < 16; ++i)
                acc = __builtin_amdgcn_mfma_f32_16x16x32_bf16(av[i], wp[i], acc, 0, 0, 0);
#pragma unroll
            for (int r = 0; r < 4; ++r) SH[wv*256 + lane*4 + r] = acc[r];
            __syncthreads();
            if (wv < 2) {   // kq4==0 waves; mt4 = wv
                float* T = SH + 2048 + wv*272;
#pragma unroll
                for (int r = 0; r < 4; ++r) {
                    float sum = SH[(wv+0)*256 + lane*4 + r] + SH[(wv+2)*256 + lane*4 + r]
                              + SH[(wv+4)*256 + lane*4 + r] + SH[(wv+6)*256 + lane*4 + r];
                    T[((lane>>4)*4 + r)*17 + (lane&15)] = sum;
                }
                __builtin_amdgcn_sched_barrier(0);
                ushort4 xr = *(const ushort4*)(Xe + (size_t)(t*32+bbd)*4096 + bid*16 + jjq*4);
                float gi = T[b_l*17 + jjq*4 + 0] + us2f(xr.x);
                float gf = T[b_l*17 + jjq*4 + 1] + us2f(xr.y);
                float gg = T[b_l*17 + jjq*4 + 2] + us2f(xr.z);
                float go = T[b_l*17 + jjq*4 + 3] + us2f(xr.w);
                float c2 = sigf(gf)*cdec + sigf(gi)*tanhf(gg);
                float h2 = sigf(go)*tanhf(c2);
                cdec = c2;
                st_wt_u16(Hd + (size_t)(t+1)*32768 + (size_t)bbd*1024 + jd, f2b(h2));
            }
            __syncthreads();
            if (tid == 0) st_wt_u32(sentH + (size_t)bid*32, (u32)(t+1));
        }
    }
}

// ---------------- generator GEMM ----------------
__global__ __launch_bounds__(256) void k_gemm_gen(const short* __restrict__ A,
                                                  const short* __restrict__ B,
                                                  const float* __restrict__ genb,
                                                  float* __restrict__ out) {
    int wave = threadIdx.x >> 6;
    int lane = threadIdx.x & 63;
    int tile = blockIdx.x * 4 + wave;
    int mt = tile & 31;
    int nt = tile >> 5;
    int m0 = mt*64, n0 = nt*64;
    int lr = lane & 15;
    int lk = (lane >> 4)*8;
    f32x4 acc[4][4] = {};
    for (int k0 = 0; k0 < 1024; k0 += 32) {
        short8 a[4], bfr[4];
#pragma unroll
        for (int mi = 0; mi < 4; ++mi)
            a[mi] = *(const short8*)(A + (long)(m0 + mi*16 + lr)*1024 + k0 + lk);
#pragma unroll
        for (int ni = 0; ni < 4; ++ni)
            bfr[ni] = *(const short8*)(B + (long)(n0 + ni*16 + lr)*1024 + k0 + lk);
#pragma unroll
        for (int mi = 0; mi < 4; ++mi)
#pragma unroll
            for (int ni = 0; ni < 4; ++ni)
                acc[mi][ni] = __builtin_amdgcn_mfma_f32_16x16x32_bf16(a[mi], bfr[ni], acc[mi][ni], 0, 0, 0);
    }
    int dcol = lane & 15;
    int drow = (lane >> 4)*4;
#pragma unroll
    for (int mi = 0; mi < 4; ++mi) {
        int mbase = m0 + mi*16 + drow;
#pragma unroll
        for (int ni = 0; ni < 4; ++ni) {
            int n = n0 + ni*16 + dcol;
            float bv = genb[n];
            f32x4 v = acc[mi][ni];
#pragma unroll
            for (int r = 0; r < 4; ++r) {
                int m = mbase + r;
                if (m < 2016) out[(long)(m + 32)*32000 + n] = v[r] + bv;
            }
        }
    }
}

// ---------------- log-softmax ----------------
__global__ __launch_bounds__(256) void k_lsm(float* __restrict__ out) {
    long row = 32 + blockIdx.x;
    float* p = out + row*32000L;
    float4* p4 = (float4*)p;
    int tid = threadIdx.x;
    __shared__ float sm[4];
    __shared__ float ss[4];
    float m = -1e30f;
    for (int i = tid; i < 8000; i += 256) {
        float4 v = p4[i];
        m = fmaxf(m, fmaxf(fmaxf(v.x, v.y), fmaxf(v.z, v.w)));
    }
    for (int off = 32; off; off >>= 1) m = fmaxf(m, __shfl_xor(m, off));
    if ((tid & 63) == 0) sm[tid >> 6] = m;
    __syncthreads();
    m = fmaxf(fmaxf(sm[0], sm[1]), fmaxf(sm[2], sm[3]));
    float s = 0;
    for (int i = tid; i < 8000; i += 256) {
        float4 v = p4[i];
        s += expf(v.x - m) + expf(v.y - m) + expf(v.z - m) + expf(v.w - m);
    }
    for (int off = 32; off; off >>= 1) s += __shfl_xor(s, off);
    if ((tid & 63) == 0) ss[tid >> 6] = s;
    __syncthreads();
    s = ss[0] + ss[1] + ss[2] + ss[3];
    float lse = m + logf(s);
    for (int i = tid; i < 8000; i += 256) {
        float4 v = p4[i];
        v.x -= lse; v.y -= lse; v.z -= lse; v.w -= lse;
        p4[i] = v;
    }
}

// ---------------- launch ----------------

extern "C" void kernel_launch(void* const* d_in, const int* in_sizes, int n_in,
                              void* d_out, int out_size, void* d_ws, size_t ws_size,
                              hipStream_t stream) {
    const float* eemb  = (const float*)d_in[0];
    const float* ewihf = (const float*)d_in[1];
    const float* ewhhf = (const float*)d_in[2];
    const float* ebf   = (const float*)d_in[3];
    const float* ewihb = (const float*)d_in[4];
    const float* ewhhb = (const float*)d_in[5];
    const float* ebb   = (const float*)d_in[6];
    const float* awi   = (const float*)d_in[7];
    const float* awo   = (const float*)d_in[8];
    const float* dwih  = (const float*)d_in[9];
    const float* dwhh  = (const float*)d_in[10];
    const float* db    = (const float*)d_in[11];
    const float* demb  = (const float*)d_in[12];
    const float* genw  = (const float*)d_in[13];
    const float* genb  = (const float*)d_in[14];
    const int* srci    = (const int*)d_in[15];
    const int* trgi    = (const int*)d_in[16];
    float* out = (float*)d_out;

    float* F = (float*)d_ws;
    u32* S       = (u32*)F;
    u32* sentE   = S;                      // 64 x 32 u32
    u32* sentSt  = S + 2048;               // 32 x 32
    u32* sentCt  = S + 3072;               // 64 x 32
    u32* sentH   = S + 5120;               // 256 x 32
    float* cfin  = F + 16384;              // 32768 floats
    u16*   U     = (u16*)(F + 49152);

    u16* Xf_    = U;                       // 2048x2048
    u16* Xb_    = U + 4194304u;            // 2048x2048
    u16* Xe_    = U + 8388608u;            // 2016x4096
    u16* WencB  = U + 16646144u;           // 2 x 2048x512
    u16* awiTB  = U + 18743296u;           // 1024x1024
    u16* awoB   = U + 19791872u;           // 1024x2048
    u16* WdecB  = U + 21889024u;           // 4096x2048
    u16* genw_b = U + 30277632u;           // 32000x1024
    u16* encBX  = U + 63045632u;           // 65 x 32x1024
    u16* Hd     = U + 65175552u;           // 65 x 32x1024
    u16* Stb    = U + 67305472u;           // 63 x 32x1024
    u16* Ctb    = U + 69369856u;           // 63 x 32x1024
    u16* encPB  = U + 71434240u;           // 2048x1024

    k_zero<<<64, 256, 0, stream>>>(F, 16384);          // sentinel lines
    k_zero<<<64, 256, 0, stream>>>((float*)encBX, 16384);
    k_zero<<<2048, 256, 0, stream>>>(out, 1024000L);

    k_xw<<<dim3(32, 64), 256, 0, stream>>>(eemb, srci, ewihf, 300, 0, ebf, Xf_, 2048, 511, 9);
    k_xw<<<dim3(32, 64), 256, 0, stream>>>(eemb, srci, ewihb, 300, 0, ebb, Xb_, 2048, 511, 9);
    k_xw<<<dim3(64, 63), 256, 0, stream>>>(demb, trgi, dwih, 1324, 1024, db, Xe_, 4096, 1023, 10);

    k_wenc<<<4096, 256, 0, stream>>>(ewhhf, WencB);
    k_wenc<<<4096, 256, 0, stream>>>(ewhhb, WencB + 1048576u);
    k_awiT<<<4096, 256, 0, stream>>>(awi, awiTB);
    k_f2b<<<2048, 256, 0, stream>>>((const float4*)awo, (ushort4*)awoB, 524288L);
    k_wdec<<<8192, 256, 0, stream>>>(dwih, dwhh, WdecB);
    k_f2b<<<8192, 256, 0, stream>>>((const float4*)genw, (ushort4*)genw_b, 8192000L);

    k_enc<<<64, 512, 0, stream>>>(Xf_, Xb_, WencB, encBX, cfin, sentE);
    k_pack<<<64, 256, 0, stream>>>(encBX, Hd);
    k_mid<<<512, 256, 0, stream>>>(encBX, awiTB, encPB);
    k_dec<<<256, 512, 0, stream>>>(Xe_, awoB, WdecB, encBX, encPB,
                                   Hd, Stb, Ctb, cfin, sentSt, sentCt, sentH);

    k_gemm_gen<<<4000, 256, 0, stream>>>((const short*)(Hd + 32768u), (const short*)genw_b, genb, out);
    k_lsm<<<2016, 256, 0, stream>>>(out);
}

// Round 10
// 3403.862 us; speedup vs baseline: 1.5566x; 1.0167x over previous
//
#include <hip/hip_runtime.h>

typedef __attribute__((ext_vector_type(8))) short short8;
typedef __attribute__((ext_vector_type(4))) float f32x4;
typedef unsigned short u16;
typedef unsigned int u32;

static __device__ __forceinline__ float sigf(float x){ return 1.0f/(1.0f+expf(-x)); }

static __device__ __forceinline__ u16 f2b(float f){
    u32 u = __float_as_uint(f);
    u += 0x7FFFu + ((u>>16)&1u);   // RNE
    return (u16)(u>>16);
}
static __device__ __forceinline__ float us2f(u16 s){ return __uint_as_float(((u32)s)<<16); }
static __device__ __forceinline__ float b2f_lo(u32 u){ return __uint_as_float(u<<16); }
static __device__ __forceinline__ float b2f_hi(u32 u){ return __uint_as_float(u & 0xffff0000u); }

static __device__ __forceinline__ void st_wt_u16(u16* p, u16 v) {
    asm volatile("global_store_short %0, %1, off sc1" :: "v"(p), "v"((u32)v) : "memory");
}
static __device__ __forceinline__ void st_wt_u32(u32* p, u32 v) {
    asm volatile("global_store_dword %0, %1, off sc1" :: "v"(p), "v"(v) : "memory");
}
static __device__ __forceinline__ u32 ld_cv(const u32* p){
    u32 v;
    asm volatile("global_load_dword %0, %1, off sc0 sc1\ns_waitcnt vmcnt(0)"
                 : "=v"(v) : "v"(p) : "memory");
    return v;
}

static __device__ __forceinline__ void hot_spin() {
    float x = 1.0f;
#pragma unroll
    for (int i = 0; i < 16; ++i) x = __builtin_fmaf(x, 1.0000001f, 1.0e-7f);
    asm volatile("" :: "v"(x));
}

// Designated waiter: polls all n producer lines (stride 32 u32 = 1 line each),
// then publishes a single release word. Everyone else polls ONLY the release
// word with ONE lane (r10: kills the 16K-poller LLC congestion of r9).
static __device__ __forceinline__ void wait_publish(const u32* base, int n, u32 tgt, u32* rel) {
    if ((int)threadIdx.x < n) {
        const u32* p = base + (size_t)threadIdx.x*32;
        while (ld_cv(p) < tgt) hot_spin();
    }
    __syncthreads();
    if (threadIdx.x == 0) st_wt_u32(rel, tgt);
}
static __device__ __forceinline__ void wait_rel(const u32* rel, u32 tgt) {
    if (threadIdx.x == 0) {
        while (ld_cv(rel) < tgt) hot_spin();
    }
    __syncthreads();
}

// ---------------- utility / conversion kernels ----------------

__global__ __launch_bounds__(256) void k_zero(float* __restrict__ p, long n) {
    for (long i = (long)blockIdx.x*256 + threadIdx.x; i < n; i += (long)gridDim.x*256) p[i] = 0.0f;
}

__global__ __launch_bounds__(256) void k_f2b(const float4* __restrict__ src,
                                             ushort4* __restrict__ dst, long n4) {
    for (long i = (long)blockIdx.x*256 + threadIdx.x; i < n4; i += (long)gridDim.x*256) {
        float4 v = src[i];
        ushort4 u;
        u.x = f2b(v.x); u.y = f2b(v.y); u.z = f2b(v.z); u.w = f2b(v.w);
        dst[i] = u;
    }
}

__global__ __launch_bounds__(256) void k_wenc(const float* __restrict__ whh, u16* __restrict__ dst) {
    int i = blockIdx.x*256 + threadIdx.x;           // 1,048,576
    int n = i >> 9, k = i & 511;
    int j = n >> 2, q = n & 3;
    dst[i] = f2b(whh[(size_t)(q*512 + j)*512 + k]);
}

__global__ __launch_bounds__(256) void k_awiT(const float* __restrict__ awi, u16* __restrict__ dst) {
    int i = blockIdx.x*256 + threadIdx.x;           // 1,048,576
    int kcol = i >> 10, n = i & 1023;
    dst[i] = f2b(awi[(size_t)n*1024 + kcol]);
}

__global__ __launch_bounds__(256) void k_wdec(const float* __restrict__ dwih,
                                              const float* __restrict__ dwhh,
                                              u16* __restrict__ dst) {
    for (long i = (long)blockIdx.x*256 + threadIdx.x; i < 8388608L; i += (long)gridDim.x*256) {
        int n = (int)(i >> 11), k = (int)(i & 2047);
        int j = n >> 2, q = n & 3;
        float v = (k < 1024) ? dwih[(size_t)(q*1024 + j)*1324 + k]
                             : dwhh[(size_t)(q*1024 + j)*1024 + (k - 1024)];
        dst[i] = f2b(v);
    }
}

__global__ __launch_bounds__(256) void k_xw(const float* __restrict__ table,
                                            const int* __restrict__ idx,
                                            const float* __restrict__ W,
                                            int wstride, int koff,
                                            const float* __restrict__ bias,
                                            u16* __restrict__ outU, int N,
                                            int jmask, int jshift) {
    __shared__ float Xs[32][300];
    int m0 = blockIdx.y * 32;
    int j0 = blockIdx.x * 64;
    for (int i = threadIdx.x; i < 32*300; i += 256) {
        int r = i/300, c = i - r*300;
        Xs[r][c] = table[(size_t)idx[m0+r]*300 + c];
    }
    __syncthreads();
    int tx = threadIdx.x & 63, ty = threadIdx.x >> 6;
    int jj = j0 + tx;
    const float* wr = W + (size_t)jj*wstride + koff;
    float acc[8] = {0,0,0,0,0,0,0,0};
    for (int k = 0; k < 300; ++k) {
        float w = wr[k];
#pragma unroll
        for (int mi = 0; mi < 8; ++mi) acc[mi] += Xs[ty*8+mi][k] * w;
    }
    float bv = bias[jj];
    int col = ((jj & jmask) << 2) | (jj >> jshift);
#pragma unroll
    for (int mi = 0; mi < 8; ++mi)
        outU[(size_t)(m0 + ty*8 + mi)*N + col] = f2b(acc[mi] + bv);
}

// ---------------- encoder (64 blocks, weights pinned in VGPRs) ----------------
__global__ __launch_bounds__(512, 1) void k_enc(
    const u16* __restrict__ Xf, const u16* __restrict__ Xb,
    const u16* __restrict__ WencB,
    u16* __restrict__ encBX, float* __restrict__ cfin,
    u32* __restrict__ sentE, u32* __restrict__ relE)
{
    __shared__ float SH[2304];
    const int tid = threadIdx.x;
    const int bid = blockIdx.x;
    const int wv = tid >> 6, lane = tid & 63;
    const int gwave = bid*8 + wv;
    const int lr = lane & 15, lk8 = (lane >> 4)*8;
    const int b_l = lane & 15, jjq = lane >> 4;
    const int g0 = bid & 48;                 // group base block
    u32* relg = relE + (size_t)(g0 >> 4)*32; // 1 release line per group

    const int dir = gwave >> 8;
    const int mt = (gwave >> 7) & 1;
    const int nt = gwave & 127;
    const int m0 = mt*16, n0 = nt*16;
    const u16* Bw = WencB + (size_t)dir*1048576 + (size_t)(n0+lr)*512 + lk8;
    const u16* Xd = dir ? Xb : Xf;
    float* T = SH + wv*272;
    const int bb = m0 + b_l;
    const int j = nt*4 + jjq;

    short8 bw[16];
#pragma unroll
    for (int i = 0; i < 16; ++i) bw[i] = *(const short8*)(Bw + i*32);

    float creg = 0.f;
    for (int t = 0; t < 64; ++t) {
        if (t > 0) {
            if (bid == g0) wait_publish(sentE + (size_t)g0*32, 16, (u32)t, relg);
            else           wait_rel(relg, (u32)t);
        }
        const int rslot = (t==0) ? 0 : (dir ? (65-t) : t);
        const u16* Ah = encBX + (size_t)rslot*32768 + (size_t)(m0+lr)*1024 + dir*512 + lk8;
        short8 av[16];
#pragma unroll
        for (int i = 0; i < 16; ++i) av[i] = *(const short8*)(Ah + i*32);
        f32x4 acc = {0.f,0.f,0.f,0.f};
#pragma unroll
        for (int i = 0; i < 16; ++i)
            acc = __builtin_amdgcn_mfma_f32_16x16x32_bf16(av[i], bw[i], acc, 0, 0, 0);
        {
            const int rb = (lane>>4)*4;
#pragma unroll
            for (int r = 0; r < 4; ++r) T[(rb+r)*17 + (lane&15)] = acc[r];
        }
        __builtin_amdgcn_sched_barrier(0);
        const int s = dir ? (63-t) : t;
        ushort4 xr = *(const ushort4*)(Xd + (size_t)(s*32+bb)*2048 + n0 + jjq*4);
        float gi = T[b_l*17 + jjq*4 + 0] + us2f(xr.x);
        float gf = T[b_l*17 + jjq*4 + 1] + us2f(xr.y);
        float gg = T[b_l*17 + jjq*4 + 2] + us2f(xr.z);
        float go = T[b_l*17 + jjq*4 + 3] + us2f(xr.w);
        float c2 = sigf(gf)*creg + sigf(gi)*tanhf(gg);
        float h2 = sigf(go)*tanhf(c2);
        creg = c2;
        st_wt_u16(encBX + (size_t)(s+1)*32768 + (size_t)bb*1024 + dir*512 + j, f2b(h2));
        __syncthreads();
        if (tid == 0) st_wt_u32(sentE + (size_t)bid*32, (u32)(t+1));
    }
    cfin[dir*16384 + bb*512 + j] = creg;
}

// ---------------- pack ----------------
__global__ __launch_bounds__(256) void k_pack(const u16* __restrict__ encBX,
                                              u16* __restrict__ Hd) {
    for (int gt = blockIdx.x*256 + threadIdx.x; gt < 32768; gt += 16384) {
        int b = gt >> 10, jj2 = gt & 1023;
        int d = jj2 & 1, k = jj2 >> 1;
        Hd[(size_t)b*1024 + jj2] = encBX[(size_t)(d ? 1 : 64)*32768 + (size_t)b*1024 + d*512 + k];
        Hd[(size_t)64*32768 + gt] = 0;
    }
}

// ---------------- encP GEMM ----------------
__global__ __launch_bounds__(256) void k_mid(const u16* __restrict__ encBX,
                                             const u16* __restrict__ awiTB,
                                             u16* __restrict__ encPB) {
    const int wv = threadIdx.x >> 6, lane = threadIdx.x & 63;
    const int lr = lane & 15, lk8 = (lane >> 4)*8;
    const u16* Abase = encBX + 32768;
#pragma unroll
    for (int ii = 0; ii < 4; ++ii) {
        int id = (blockIdx.x*4 + wv)*4 + ii;
        int mt2 = id >> 6, nt2 = id & 63;
        int m0 = mt2*16, n0 = nt2*16;
        const u16* Ar = Abase + (size_t)(m0+lr)*1024 + lk8;
        const u16* Br = awiTB + (size_t)(n0+lr)*1024 + lk8;
        f32x4 acc = {0.f,0.f,0.f,0.f};
#pragma unroll 8
        for (int i = 0; i < 32; ++i) {
            short8 av = *(const short8*)(Ar + i*32);
            short8 bv = *(const short8*)(Br + i*32);
            acc = __builtin_amdgcn_mfma_f32_16x16x32_bf16(av, bv, acc, 0, 0, 0);
        }
        int col = n0 + (lane&15);
        int rb = m0 + (lane>>4)*4;
#pragma unroll
        for (int r = 0; r < 4; ++r)
            encPB[(size_t)(rb+r)*1024 + col] = f2b(acc[r]);
    }
}

// ---------------- decoder (256 blocks, weights pinned in VGPRs) ----------------
// P2: blocks 0-31. P3: blocks 32-95. P4: all 256.
// Release publishers: relH by block 0, relSt by block 32, relCt by block 96.
__global__ __launch_bounds__(512, 1) void k_dec(
    const u16* __restrict__ Xe,
    const u16* __restrict__ awoB, const u16* __restrict__ WdecB,
    const u16* __restrict__ encBX, const u16* __restrict__ encPB,
    u16* __restrict__ Hd, u16* __restrict__ Stb, u16* __restrict__ Ctb,
    const float* __restrict__ cfin,
    u32* __restrict__ sentSt, u32* __restrict__ sentCt, u32* __restrict__ sentH,
    u32* __restrict__ relSt, u32* __restrict__ relCt, u32* __restrict__ relH)
{
    __shared__ float SH[2592];
    const int tid = threadIdx.x;
    const int bid = blockIdx.x;
    const int wv = tid >> 6, lane = tid & 63;
    const int lr = lane & 15, lk8 = (lane >> 4)*8;
    const int b_l = lane & 15, jjq = lane >> 4;

    const int mt4 = wv & 1, kq4 = wv >> 1;
    const int m0d = mt4*16;
    const int bbd = m0d + b_l;
    const int jd = bid*4 + jjq;
    float cdec = cfin[(jd&1)*16384 + bbd*512 + (jd>>1)];

    short8 wp[16];
#pragma unroll
    for (int i = 0; i < 16; ++i)
        wp[i] = *(const short8*)(WdecB + (size_t)(bid*16+lr)*2048 + kq4*512 + lk8 + i*32);

    const bool midP3 = (bid >= 32 && bid < 96);
    const int nt3 = bid - 32;
    const int mt3 = wv & 1, kq3 = wv >> 1;
    short8 w3[16];
    if (midP3) {
#pragma unroll
        for (int i = 0; i < 16; ++i)
            w3[i] = *(const short8*)(awoB + (size_t)(nt3*16+lr)*2048 + kq3*512 + lk8 + i*32);
    }

    for (int t = 0; t < 63; ++t) {
        // ---- P2: attention -> s_tilde ----
        if (bid < 32) {
            if (t > 0) {
                if (bid == 0) wait_publish(sentH, 256, (u32)t, relH);
                else          wait_rel(relH, (u32)t);
            }
            const int bbb = bid;
            float* hsh = SH; float* red = SH + 1024; float* sc = SH + 1536;
            {
                u32 u = ((const u32*)Hd)[(size_t)t*16384 + bbb*512 + tid];
                hsh[2*tid]   = b2f_lo(u);
                hsh[2*tid+1] = b2f_hi(u);
            }
            __syncthreads();
            {
                int s = tid >> 3, p = tid & 7;
                const uint4* ep = (const uint4*)(encPB + (size_t)(s*32+bbb)*1024 + p*128);
                uint4 er[16];
#pragma unroll
                for (int q8 = 0; q8 < 16; ++q8) er[q8] = ep[q8];
                const float* hk = hsh + p*128;
                float a0=0,a1=0,a2=0,a3=0;
#pragma unroll
                for (int q8 = 0; q8 < 16; ++q8) {
                    uint4 u = er[q8];
                    a0 += b2f_lo(u.x)*hk[q8*8+0] + b2f_hi(u.x)*hk[q8*8+1];
                    a1 += b2f_lo(u.y)*hk[q8*8+2] + b2f_hi(u.y)*hk[q8*8+3];
                    a2 += b2f_lo(u.z)*hk[q8*8+4] + b2f_hi(u.z)*hk[q8*8+5];
                    a3 += b2f_lo(u.w)*hk[q8*8+6] + b2f_hi(u.w)*hk[q8*8+7];
                }
                red[tid] = (a0+a1)+(a2+a3);
            }
            __syncthreads();
            if (tid < 64) {
                float v = 0;
#pragma unroll
                for (int pp = 0; pp < 8; ++pp) v += red[tid*8+pp];
                float m = v;
                for (int off = 32; off; off >>= 1) m = fmaxf(m, __shfl_xor(m, off));
                float e = expf(v - m);
                float ss = e;
                for (int off = 32; off; off >>= 1) ss += __shfl_xor(ss, off);
                sc[tid] = e / ss;
            }
            __syncthreads();
            {
                const u32* eb = (const u32*)encBX + 16384 + bbb*512 + tid;
                u32 ebv[64];
#pragma unroll
                for (int s2 = 0; s2 < 64; ++s2) ebv[s2] = eb[(size_t)s2*16384];
                float st0 = 0, st1 = 0;
#pragma unroll
                for (int s2 = 0; s2 < 64; ++s2) {
                    float w = sc[s2];
                    st0 += w*b2f_lo(ebv[s2]); st1 += w*b2f_hi(ebv[s2]);
                }
                u32 pk = (u32)f2b(st0) | ((u32)f2b(st1) << 16);
                st_wt_u32((u32*)Stb + (size_t)t*16384 + bbb*512 + tid, pk);
            }
            __syncthreads();
            if (tid == 0) st_wt_u32(sentSt + (size_t)bid*32, (u32)(t+1));
        }

        // ---- P3: c_t = tanh([s_tilde, h] @ awo^T) ----
        if (midP3) {
            if (bid == 32) wait_publish(sentSt, 32, (u32)(t+1), relSt);
            else           wait_rel(relSt, (u32)(t+1));
            const u16* Ab = (kq3 < 2)
                ? (Stb + (size_t)t*32768 + (size_t)(mt3*16+lr)*1024 + kq3*512 + lk8)
                : (Hd  + (size_t)t*32768 + (size_t)(mt3*16+lr)*1024 + (kq3-2)*512 + lk8);
            short8 av[16];
#pragma unroll
            for (int i = 0; i < 16; ++i) av[i] = *(const short8*)(Ab + i*32);
            f32x4 acc = {0.f,0.f,0.f,0.f};
#pragma unroll
            for (int i = 0; i < 16; ++i)
                acc = __builtin_amdgcn_mfma_f32_16x16x32_bf16(av[i], w3[i], acc, 0, 0, 0);
#pragma unroll
            for (int r = 0; r < 4; ++r) SH[wv*256 + lane*4 + r] = acc[r];
            __syncthreads();
            if (wv < 2) {
#pragma unroll
                for (int r = 0; r < 4; ++r) {
                    float sum = SH[(wv+0)*256 + lane*4 + r] + SH[(wv+2)*256 + lane*4 + r]
                              + SH[(wv+4)*256 + lane*4 + r] + SH[(wv+6)*256 + lane*4 + r];
                    int bq = wv*16 + (lane>>4)*4 + r;
                    st_wt_u16(Ctb + (size_t)t*32768 + (size_t)bq*1024 + nt3*16 + (lane&15),
                              f2b(tanhf(sum)));
                }
            }
            __syncthreads();
            if (tid == 0) st_wt_u32(sentCt + (size_t)(bid-32)*32, (u32)(t+1));
        }

        // ---- P4: gates = [c_t, h] @ Wdec^T + Xe; cell update ----
        if (bid == 96) wait_publish(sentCt, 64, (u32)(t+1), relCt);
        else           wait_rel(relCt, (u32)(t+1));
        {
            const u16* Ab = (kq4 < 2)
                ? (Ctb + (size_t)t*32768 + (size_t)(m0d+lr)*1024 + kq4*512 + lk8)
                : (Hd  + (size_t)t*32768 + (size_t)(m0d+lr)*1024 + (kq4-2)*512 + lk8);
            short8 av[16];
#pragma unroll
            for (int i = 0; i < 16; ++i) av[i] = *(const short8*)(Ab + i*32);
            f32x4 acc = {0.f,0.f,0.f,0.f};
#pragma unroll
            for (int i = 0; i < 16; ++i)
                acc = __builtin_amdgcn_mfma_f32_16x16x32_bf16(av[i], wp[i], acc, 0, 0, 0);
#pragma unroll
            for (int r = 0; r < 4; ++r) SH[wv*256 + lane*4 + r] = acc[r];
            __syncthreads();
            if (wv < 2) {
                float* T = SH + 2048 + wv*272;
#pragma unroll
                for (int r = 0; r < 4; ++r) {
                    float sum = SH[(wv+0)*256 + lane*4 + r] + SH[(wv+2)*256 + lane*4 + r]
                              + SH[(wv+4)*256 + lane*4 + r] + SH[(wv+6)*256 + lane*4 + r];
                    T[((lane>>4)*4 + r)*17 + (lane&15)] = sum;
                }
                __builtin_amdgcn_sched_barrier(0);
                ushort4 xr = *(const ushort4*)(Xe + (size_t)(t*32+bbd)*4096 + bid*16 + jjq*4);
                float gi = T[b_l*17 + jjq*4 + 0] + us2f(xr.x);
                float gf = T[b_l*17 + jjq*4 + 1] + us2f(xr.y);
                float gg = T[b_l*17 + jjq*4 + 2] + us2f(xr.z);
                float go = T[b_l*17 + jjq*4 + 3] + us2f(xr.w);
                float c2 = sigf(gf)*cdec + sigf(gi)*tanhf(gg);
                float h2 = sigf(go)*tanhf(c2);
                cdec = c2;
                st_wt_u16(Hd + (size_t)(t+1)*32768 + (size_t)bbd*1024 + jd, f2b(h2));
            }
            __syncthreads();
            if (tid == 0) st_wt_u32(sentH + (size_t)bid*32, (u32)(t+1));
        }
    }
}

// ---------------- generator GEMM ----------------
__global__ __launch_bounds__(256) void k_gemm_gen(const short* __restrict__ A,
                                                  const short* __restrict__ B,
                                                  const float* __restrict__ genb,
                                                  float* __restrict__ out) {
    int wave = threadIdx.x >> 6;
    int lane = threadIdx.x & 63;
    int tile = blockIdx.x * 4 + wave;
    int mt = tile & 31;
    int nt = tile >> 5;
    int m0 = mt*64, n0 = nt*64;
    int lr = lane & 15;
    int lk = (lane >> 4)*8;
    f32x4 acc[4][4] = {};
    for (int k0 = 0; k0 < 1024; k0 += 32) {
        short8 a[4], bfr[4];
#pragma unroll
        for (int mi = 0; mi < 4; ++mi)
            a[mi] = *(const short8*)(A + (long)(m0 + mi*16 + lr)*1024 + k0 + lk);
#pragma unroll
        for (int ni = 0; ni < 4; ++ni)
            bfr[ni] = *(const short8*)(B + (long)(n0 + ni*16 + lr)*1024 + k0 + lk);
#pragma unroll
        for (int mi = 0; mi < 4; ++mi)
#pragma unroll
            for (int ni = 0; ni < 4; ++ni)
                acc[mi][ni] = __builtin_amdgcn_mfma_f32_16x16x32_bf16(a[mi], bfr[ni], acc[mi][ni], 0, 0, 0);
    }
    int dcol = lane & 15;
    int drow = (lane >> 4)*4;
#pragma unroll
    for (int mi = 0; mi < 4; ++mi) {
        int mbase = m0 + mi*16 + drow;
#pragma unroll
        for (int ni = 0; ni < 4; ++ni) {
            int n = n0 + ni*16 + dcol;
            float bv = genb[n];
            f32x4 v = acc[mi][ni];
#pragma unroll
            for (int r = 0; r < 4; ++r) {
                int m = mbase + r;
                if (m < 2016) out[(long)(m + 32)*32000 + n] = v[r] + bv;
            }
        }
    }
}

// ---------------- log-softmax ----------------
__global__ __launch_bounds__(256) void k_lsm(float* __restrict__ out) {
    long row = 32 + blockIdx.x;
    float* p = out + row*32000L;
    float4* p4 = (float4*)p;
    int tid = threadIdx.x;
    __shared__ float sm[4];
    __shared__ float ss[4];
    float m = -1e30f;
    for (int i = tid; i < 8000; i += 256) {
        float4 v = p4[i];
        m = fmaxf(m, fmaxf(fmaxf(v.x, v.y), fmaxf(v.z, v.w)));
    }
    for (int off = 32; off; off >>= 1) m = fmaxf(m, __shfl_xor(m, off));
    if ((tid & 63) == 0) sm[tid >> 6] = m;
    __syncthreads();
    m = fmaxf(fmaxf(sm[0], sm[1]), fmaxf(sm[2], sm[3]));
    float s = 0;
    for (int i = tid; i < 8000; i += 256) {
        float4 v = p4[i];
        s += expf(v.x - m) + expf(v.y - m) + expf(v.z - m) + expf(v.w - m);
    }
    for (int off = 32; off; off >>= 1) s += __shfl_xor(s, off);
    if ((tid & 63) == 0) ss[tid >> 6] = s;
    __syncthreads();
    s = ss[0] + ss[1] + ss[2] + ss[3];
    float lse = m + logf(s);
    for (int i = tid; i < 8000; i += 256) {
        float4 v = p4[i];
        v.x -= lse; v.y -= lse; v.z -= lse; v.w -= lse;
        p4[i] = v;
    }
}

// ---------------- launch ----------------

extern "C" void kernel_launch(void* const* d_in, const int* in_sizes, int n_in,
                              void* d_out, int out_size, void* d_ws, size_t ws_size,
                              hipStream_t stream) {
    const float* eemb  = (const float*)d_in[0];
    const float* ewihf = (const float*)d_in[1];
    const float* ewhhf = (const float*)d_in[2];
    const float* ebf   = (const float*)d_in[3];
    const float* ewihb = (const float*)d_in[4];
    const float* ewhhb = (const float*)d_in[5];
    const float* ebb   = (const float*)d_in[6];
    const float* awi   = (const float*)d_in[7];
    const float* awo   = (const float*)d_in[8];
    const float* dwih  = (const float*)d_in[9];
    const float* dwhh  = (const float*)d_in[10];
    const float* db    = (const float*)d_in[11];
    const float* demb  = (const float*)d_in[12];
    const float* genw  = (const float*)d_in[13];
    const float* genb  = (const float*)d_in[14];
    const int* srci    = (const int*)d_in[15];
    const int* trgi    = (const int*)d_in[16];
    float* out = (float*)d_out;

    float* F = (float*)d_ws;
    u32* S       = (u32*)F;
    u32* sentE   = S;                      // 64 x 32
    u32* sentSt  = S + 2048;               // 32 x 32
    u32* sentCt  = S + 3072;               // 64 x 32
    u32* sentH   = S + 5120;               // 256 x 32
    u32* relE    = S + 13312;              // 4 x 32
    u32* relSt   = S + 13440;              // 32
    u32* relCt   = S + 13472;              // 32
    u32* relH    = S + 13504;              // 32
    float* cfin  = F + 16384;              // 32768 floats
    u16*   U     = (u16*)(F + 49152);

    u16* Xf_    = U;                       // 2048x2048
    u16* Xb_    = U + 4194304u;            // 2048x2048
    u16* Xe_    = U + 8388608u;            // 2016x4096
    u16* WencB  = U + 16646144u;           // 2 x 2048x512
    u16* awiTB  = U + 18743296u;           // 1024x1024
    u16* awoB   = U + 19791872u;           // 1024x2048
    u16* WdecB  = U + 21889024u;           // 4096x2048
    u16* genw_b = U + 30277632u;           // 32000x1024
    u16* encBX  = U + 63045632u;           // 65 x 32x1024
    u16* Hd     = U + 65175552u;           // 65 x 32x1024
    u16* Stb    = U + 67305472u;           // 63 x 32x1024
    u16* Ctb    = U + 69369856u;           // 63 x 32x1024
    u16* encPB  = U + 71434240u;           // 2048x1024

    k_zero<<<64, 256, 0, stream>>>(F, 16384);          // sentinels + release lines
    k_zero<<<64, 256, 0, stream>>>((float*)encBX, 16384);
    k_zero<<<2048, 256, 0, stream>>>(out, 1024000L);

    k_xw<<<dim3(32, 64), 256, 0, stream>>>(eemb, srci, ewihf, 300, 0, ebf, Xf_, 2048, 511, 9);
    k_xw<<<dim3(32, 64), 256, 0, stream>>>(eemb, srci, ewihb, 300, 0, ebb, Xb_, 2048, 511, 9);
    k_xw<<<dim3(64, 63), 256, 0, stream>>>(demb, trgi, dwih, 1324, 1024, db, Xe_, 4096, 1023, 10);

    k_wenc<<<4096, 256, 0, stream>>>(ewhhf, WencB);
    k_wenc<<<4096, 256, 0, stream>>>(ewhhb, WencB + 1048576u);
    k_awiT<<<4096, 256, 0, stream>>>(awi, awiTB);
    k_f2b<<<2048, 256, 0, stream>>>((const float4*)awo, (ushort4*)awoB, 524288L);
    k_wdec<<<8192, 256, 0, stream>>>(dwih, dwhh, WdecB);
    k_f2b<<<8192, 256, 0, stream>>>((const float4*)genw, (ushort4*)genw_b, 8192000L);

    k_enc<<<64, 512, 0, stream>>>(Xf_, Xb_, WencB, encBX, cfin, sentE, relE);
    k_pack<<<64, 256, 0, stream>>>(encBX, Hd);
    k_mid<<<512, 256, 0, stream>>>(encBX, awiTB, encPB);
    k_dec<<<256, 512, 0, stream>>>(Xe_, awoB, WdecB, encBX, encPB,
                                   Hd, Stb, Ctb, cfin, sentSt, sentCt, sentH,
                                   relSt, relCt, relH);

    k_gemm_gen<<<4000, 256, 0, stream>>>((const short*)(Hd + 32768u), (const short*)genw_b, genb, out);
    k_lsm<<<2016, 256, 0, stream>>>(out);
}

// Round 11
// 3361.550 us; speedup vs baseline: 1.5762x; 1.0126x over previous
//
#include <hip/hip_runtime.h>

typedef __attribute__((ext_vector_type(8))) short short8;
typedef __attribute__((ext_vector_type(4))) float f32x4;
typedef unsigned short u16;
typedef unsigned int u32;

static __device__ __forceinline__ float sigf(float x){ return 1.0f/(1.0f+expf(-x)); }

static __device__ __forceinline__ u16 f2b(float f){
    u32 u = __float_as_uint(f);
    u += 0x7FFFu + ((u>>16)&1u);   // RNE
    return (u16)(u>>16);
}
static __device__ __forceinline__ float us2f(u16 s){ return __uint_as_float(((u32)s)<<16); }
static __device__ __forceinline__ float b2f_lo(u32 u){ return __uint_as_float(u<<16); }
static __device__ __forceinline__ float b2f_hi(u32 u){ return __uint_as_float(u & 0xffff0000u); }

static __device__ __forceinline__ void st_wt_u16(u16* p, u16 v) {
    asm volatile("global_store_short %0, %1, off sc1" :: "v"(p), "v"((u32)v) : "memory");
}
static __device__ __forceinline__ void st_wt_u32(u32* p, u32 v) {
    asm volatile("global_store_dword %0, %1, off sc1" :: "v"(p), "v"(v) : "memory");
}
static __device__ __forceinline__ u32 ld_cv(const u32* p){
    u32 v;
    asm volatile("global_load_dword %0, %1, off sc0 sc1\ns_waitcnt vmcnt(0)"
                 : "=v"(v) : "v"(p) : "memory");
    return v;
}

static __device__ __forceinline__ void hot_spin() {
    float x = 1.0f;
#pragma unroll
    for (int i = 0; i < 16; ++i) x = __builtin_fmaf(x, 1.0000001f, 1.0e-7f);
    asm volatile("" :: "v"(x));
}

// Designated waiter publishes a single release word; others poll only that.
static __device__ __forceinline__ void wait_publish(const u32* base, int n, u32 tgt, u32* rel) {
    if ((int)threadIdx.x < n) {
        const u32* p = base + (size_t)threadIdx.x*32;
        while (ld_cv(p) < tgt) hot_spin();
    }
    __syncthreads();
    if (threadIdx.x == 0) st_wt_u32(rel, tgt);
}
static __device__ __forceinline__ void wait_rel(const u32* rel, u32 tgt) {
    if (threadIdx.x == 0) {
        while (ld_cv(rel) < tgt) hot_spin();
    }
    __syncthreads();
}

// ---------------- diagnostic: 2-block ping-pong, 256 round trips ----------------
// rocprof duration / 512 = one-way sc1-store -> sc0sc1-poll edge cost.
__global__ __launch_bounds__(64) void k_ping(u32* ping, u32* pong) {
    if (threadIdx.x != 0) return;
    if (blockIdx.x == 0) {
        for (u32 i = 1; i <= 256; ++i) {
            st_wt_u32(ping, i);
            while (ld_cv(pong) < i) {}
        }
    } else {
        for (u32 i = 1; i <= 256; ++i) {
            while (ld_cv(ping) < i) {}
            st_wt_u32(pong, i);
        }
    }
}

// ---------------- utility / conversion kernels ----------------

__global__ __launch_bounds__(256) void k_zero(float* __restrict__ p, long n) {
    for (long i = (long)blockIdx.x*256 + threadIdx.x; i < n; i += (long)gridDim.x*256) p[i] = 0.0f;
}

__global__ __launch_bounds__(256) void k_f2b(const float4* __restrict__ src,
                                             ushort4* __restrict__ dst, long n4) {
    for (long i = (long)blockIdx.x*256 + threadIdx.x; i < n4; i += (long)gridDim.x*256) {
        float4 v = src[i];
        ushort4 u;
        u.x = f2b(v.x); u.y = f2b(v.y); u.z = f2b(v.z); u.w = f2b(v.w);
        dst[i] = u;
    }
}

__global__ __launch_bounds__(256) void k_wenc(const float* __restrict__ whh, u16* __restrict__ dst) {
    int i = blockIdx.x*256 + threadIdx.x;           // 1,048,576
    int n = i >> 9, k = i & 511;
    int j = n >> 2, q = n & 3;
    dst[i] = f2b(whh[(size_t)(q*512 + j)*512 + k]);
}

__global__ __launch_bounds__(256) void k_awiT(const float* __restrict__ awi, u16* __restrict__ dst) {
    int i = blockIdx.x*256 + threadIdx.x;           // 1,048,576
    int kcol = i >> 10, n = i & 1023;
    dst[i] = f2b(awi[(size_t)n*1024 + kcol]);
}

__global__ __launch_bounds__(256) void k_wdec(const float* __restrict__ dwih,
                                              const float* __restrict__ dwhh,
                                              u16* __restrict__ dst) {
    for (long i = (long)blockIdx.x*256 + threadIdx.x; i < 8388608L; i += (long)gridDim.x*256) {
        int n = (int)(i >> 11), k = (int)(i & 2047);
        int j = n >> 2, q = n & 3;
        float v = (k < 1024) ? dwih[(size_t)(q*1024 + j)*1324 + k]
                             : dwhh[(size_t)(q*1024 + j)*1024 + (k - 1024)];
        dst[i] = f2b(v);
    }
}

__global__ __launch_bounds__(256) void k_xw(const float* __restrict__ table,
                                            const int* __restrict__ idx,
                                            const float* __restrict__ W,
                                            int wstride, int koff,
                                            const float* __restrict__ bias,
                                            u16* __restrict__ outU, int N,
                                            int jmask, int jshift) {
    __shared__ float Xs[32][300];
    int m0 = blockIdx.y * 32;
    int j0 = blockIdx.x * 64;
    for (int i = threadIdx.x; i < 32*300; i += 256) {
        int r = i/300, c = i - r*300;
        Xs[r][c] = table[(size_t)idx[m0+r]*300 + c];
    }
    __syncthreads();
    int tx = threadIdx.x & 63, ty = threadIdx.x >> 6;
    int jj = j0 + tx;
    const float* wr = W + (size_t)jj*wstride + koff;
    float acc[8] = {0,0,0,0,0,0,0,0};
    for (int k = 0; k < 300; ++k) {
        float w = wr[k];
#pragma unroll
        for (int mi = 0; mi < 8; ++mi) acc[mi] += Xs[ty*8+mi][k] * w;
    }
    float bv = bias[jj];
    int col = ((jj & jmask) << 2) | (jj >> jshift);
#pragma unroll
    for (int mi = 0; mi < 8; ++mi)
        outU[(size_t)(m0 + ty*8 + mi)*N + col] = f2b(acc[mi] + bv);
}

// ---------------- encoder (64 blocks, weights pinned in VGPRs) ----------------
__global__ __launch_bounds__(512, 1) void k_enc(
    const u16* __restrict__ Xf, const u16* __restrict__ Xb,
    const u16* __restrict__ WencB,
    u16* __restrict__ encBX, float* __restrict__ cfin,
    u32* __restrict__ sentE, u32* __restrict__ relE)
{
    __shared__ float SH[2304];
    const int tid = threadIdx.x;
    const int bid = blockIdx.x;
    const int wv = tid >> 6, lane = tid & 63;
    const int gwave = bid*8 + wv;
    const int lr = lane & 15, lk8 = (lane >> 4)*8;
    const int b_l = lane & 15, jjq = lane >> 4;
    const int g0 = bid & 48;
    u32* relg = relE + (size_t)(g0 >> 4)*32;

    const int dir = gwave >> 8;
    const int mt = (gwave >> 7) & 1;
    const int nt = gwave & 127;
    const int m0 = mt*16, n0 = nt*16;
    const u16* Bw = WencB + (size_t)dir*1048576 + (size_t)(n0+lr)*512 + lk8;
    const u16* Xd = dir ? Xb : Xf;
    float* T = SH + wv*272;
    const int bb = m0 + b_l;
    const int j = nt*4 + jjq;

    short8 bw[16];
#pragma unroll
    for (int i = 0; i < 16; ++i) bw[i] = *(const short8*)(Bw + i*32);

    float creg = 0.f;
    for (int t = 0; t < 64; ++t) {
        if (t > 0) {
            if (bid == g0) wait_publish(sentE + (size_t)g0*32, 16, (u32)t, relg);
            else           wait_rel(relg, (u32)t);
        }
        const int rslot = (t==0) ? 0 : (dir ? (65-t) : t);
        const u16* Ah = encBX + (size_t)rslot*32768 + (size_t)(m0+lr)*1024 + dir*512 + lk8;
        short8 av[16];
#pragma unroll
        for (int i = 0; i < 16; ++i) av[i] = *(const short8*)(Ah + i*32);
        f32x4 acc = {0.f,0.f,0.f,0.f};
#pragma unroll
        for (int i = 0; i < 16; ++i)
            acc = __builtin_amdgcn_mfma_f32_16x16x32_bf16(av[i], bw[i], acc, 0, 0, 0);
        {
            const int rb = (lane>>4)*4;
#pragma unroll
            for (int r = 0; r < 4; ++r) T[(rb+r)*17 + (lane&15)] = acc[r];
        }
        __builtin_amdgcn_sched_barrier(0);
        const int s = dir ? (63-t) : t;
        ushort4 xr = *(const ushort4*)(Xd + (size_t)(s*32+bb)*2048 + n0 + jjq*4);
        float gi = T[b_l*17 + jjq*4 + 0] + us2f(xr.x);
        float gf = T[b_l*17 + jjq*4 + 1] + us2f(xr.y);
        float gg = T[b_l*17 + jjq*4 + 2] + us2f(xr.z);
        float go = T[b_l*17 + jjq*4 + 3] + us2f(xr.w);
        float c2 = sigf(gf)*creg + sigf(gi)*tanhf(gg);
        float h2 = sigf(go)*tanhf(c2);
        creg = c2;
        st_wt_u16(encBX + (size_t)(s+1)*32768 + (size_t)bb*1024 + dir*512 + j, f2b(h2));
        __syncthreads();
        if (tid == 0) st_wt_u32(sentE + (size_t)bid*32, (u32)(t+1));
    }
    cfin[dir*16384 + bb*512 + j] = creg;
}

// ---------------- pack ----------------
__global__ __launch_bounds__(256) void k_pack(const u16* __restrict__ encBX,
                                              u16* __restrict__ Hd) {
    for (int gt = blockIdx.x*256 + threadIdx.x; gt < 32768; gt += 16384) {
        int b = gt >> 10, jj2 = gt & 1023;
        int d = jj2 & 1, k = jj2 >> 1;
        Hd[(size_t)b*1024 + jj2] = encBX[(size_t)(d ? 1 : 64)*32768 + (size_t)b*1024 + d*512 + k];
        Hd[(size_t)64*32768 + gt] = 0;
    }
}

// ---------------- encP + EOA GEMMs ----------------
// ids 0..8191: encP[s*32+b][n] = enc_out . awi^T-bilinear (as before)
// ids 8192..16383: EOA[b][s][n] = enc_out[s,b,:] . awo[n,0:1024]
__global__ __launch_bounds__(256) void k_mid(const u16* __restrict__ encBX,
                                             const u16* __restrict__ awiTB,
                                             const u16* __restrict__ awoB,
                                             u16* __restrict__ encPB,
                                             u16* __restrict__ EOAb) {
    const int wv = threadIdx.x >> 6, lane = threadIdx.x & 63;
    const int lr = lane & 15, lk8 = (lane >> 4)*8;
    const u16* Abase = encBX + 32768;
#pragma unroll
    for (int ii = 0; ii < 4; ++ii) {
        int id = (blockIdx.x*4 + wv)*4 + ii;
        int eoa = id >> 13;           // 0: encP, 1: EOA
        int id2 = id & 8191;
        int mt2 = id2 >> 6, nt2 = id2 & 63;
        int m0 = mt2*16, n0 = nt2*16;
        const u16* Ar = Abase + (size_t)(m0+lr)*1024 + lk8;
        const u16* Br = eoa ? (awoB + (size_t)(n0+lr)*2048 + lk8)
                            : (awiTB + (size_t)(n0+lr)*1024 + lk8);
        f32x4 acc = {0.f,0.f,0.f,0.f};
#pragma unroll 8
        for (int i = 0; i < 32; ++i) {
            short8 av = *(const short8*)(Ar + i*32);
            short8 bv = *(const short8*)(Br + i*32);
            acc = __builtin_amdgcn_mfma_f32_16x16x32_bf16(av, bv, acc, 0, 0, 0);
        }
        int col = n0 + (lane&15);
        int rb = m0 + (lane>>4)*4;
#pragma unroll
        for (int r = 0; r < 4; ++r) {
            int row = rb + r;
            if (eoa) {
                int b = row & 31, s = row >> 5;
                EOAb[((size_t)b*64 + s)*1024 + col] = f2b(acc[r]);
            } else {
                encPB[(size_t)row*1024 + col] = f2b(acc[r]);
            }
        }
    }
}

// ---------------- decoder: 2 global phases/step ----------------
// Phase A (needs h[t]): blocks 0-31 = attention P->PEO (VALU); blocks 32-95 = hA GEMM.
// Phase B (needs PEO+hA): all 256 blocks: c_t = tanh(PEO+hA) in LDS, gates MFMA, cell.
__global__ __launch_bounds__(512, 1) void k_dec(
    const u16* __restrict__ Xe,
    const u16* __restrict__ awoB, const u16* __restrict__ WdecB,
    const u16* __restrict__ encPB, const u16* __restrict__ EOAb,
    u16* __restrict__ Hd, u16* __restrict__ PEOb, u16* __restrict__ hAb,
    const float* __restrict__ cfin,
    u32* __restrict__ sentA, u32* __restrict__ sentH,
    u32* __restrict__ relA, u32* __restrict__ relH)
{
    __shared__ float SH[2592];
    __shared__ u32 CT[16512];          // c_t bf16-pairs [32 rows][516 u32] (padded)
    const int tid = threadIdx.x;
    const int bid = blockIdx.x;
    const int wv = tid >> 6, lane = tid & 63;
    const int lr = lane & 15, lk8 = (lane >> 4)*8;
    const int b_l = lane & 15, jjq = lane >> 4;

    // phase B assignment
    const int mt4 = wv & 1, kq4 = wv >> 1;
    const int m0d = mt4*16;
    const int bbd = m0d + b_l;
    const int jd = bid*4 + jjq;
    float cdec = cfin[(jd&1)*16384 + bbd*512 + (jd>>1)];

    short8 wp[16];
#pragma unroll
    for (int i = 0; i < 16; ++i)
        wp[i] = *(const short8*)(WdecB + (size_t)(bid*16+lr)*2048 + kq4*512 + lk8 + i*32);

    // phase A hA assignment (blocks 32..95): 16 cols each, 2 mt x 4 kq (K=256)
    const bool isHA = (bid >= 32 && bid < 96);
    const int nth = bid - 32;
    const int mth = wv & 1, kqh = wv >> 1;
    short8 wh[8];
    if (isHA) {
#pragma unroll
        for (int i = 0; i < 8; ++i)
            wh[i] = *(const short8*)(awoB + (size_t)(nth*16+lr)*2048 + 1024 + kqh*256 + lk8 + i*32);
    }

    for (int t = 0; t < 63; ++t) {
        // ======== Phase A ========
        if (bid < 96) {
            if (t > 0) {
                if (bid == 0) wait_publish(sentH, 256, (u32)t, relH);
                else          wait_rel(relH, (u32)t);
            }
            if (bid < 32) {
                // attention for item b: scores -> softmax -> PEO = sum_s P[s]*EOA[b][s][:]
                const int b = bid;
                float* hsh = SH; float* red = SH + 1024; float* sc = SH + 1536;
                {
                    u32 u = ((const u32*)Hd)[(size_t)t*16384 + b*512 + tid];
                    hsh[2*tid]   = b2f_lo(u);
                    hsh[2*tid+1] = b2f_hi(u);
                }
                __syncthreads();
                {
                    int s = tid >> 3, p = tid & 7;
                    const uint4* ep = (const uint4*)(encPB + (size_t)(s*32+b)*1024 + p*128);
                    const float* hk = hsh + p*128;
                    float a0=0,a1=0,a2=0,a3=0;
#pragma unroll 4
                    for (int q8 = 0; q8 < 16; ++q8) {
                        uint4 u = ep[q8];
                        a0 += b2f_lo(u.x)*hk[q8*8+0] + b2f_hi(u.x)*hk[q8*8+1];
                        a1 += b2f_lo(u.y)*hk[q8*8+2] + b2f_hi(u.y)*hk[q8*8+3];
                        a2 += b2f_lo(u.z)*hk[q8*8+4] + b2f_hi(u.z)*hk[q8*8+5];
                        a3 += b2f_lo(u.w)*hk[q8*8+6] + b2f_hi(u.w)*hk[q8*8+7];
                    }
                    red[tid] = (a0+a1)+(a2+a3);
                }
                __syncthreads();
                if (tid < 64) {
                    float v = 0;
#pragma unroll
                    for (int pp = 0; pp < 8; ++pp) v += red[tid*8+pp];
                    float m = v;
                    for (int off = 32; off; off >>= 1) m = fmaxf(m, __shfl_xor(m, off));
                    float e = expf(v - m);
                    float ss = e;
                    for (int off = 32; off; off >>= 1) ss += __shfl_xor(ss, off);
                    sc[tid] = e / ss;
                }
                __syncthreads();
                {
                    const u32* eo = (const u32*)EOAb + (size_t)b*32768 + tid;  // [s][512 u32]
                    float p0 = 0, p1 = 0;
#pragma unroll 8
                    for (int s = 0; s < 64; ++s) {
                        u32 u = eo[(size_t)s*512];
                        float w = sc[s];
                        p0 += w*b2f_lo(u); p1 += w*b2f_hi(u);
                    }
                    u32 pk = (u32)f2b(p0) | ((u32)f2b(p1) << 16);
                    st_wt_u32((u32*)PEOb + (size_t)t*16384 + b*512 + tid, pk);
                }
            } else {
                // hA = h @ awoB2^T  (M=32 items x N=16 cols x K=1024, kq-split)
                const u16* Ah = Hd + (size_t)t*32768 + (size_t)(mth*16+lr)*1024 + kqh*256 + lk8;
                short8 av[8];
#pragma unroll
                for (int i = 0; i < 8; ++i) av[i] = *(const short8*)(Ah + i*32);
                f32x4 acc = {0.f,0.f,0.f,0.f};
#pragma unroll
                for (int i = 0; i < 8; ++i)
                    acc = __builtin_amdgcn_mfma_f32_16x16x32_bf16(av[i], wh[i], acc, 0, 0, 0);
#pragma unroll
                for (int r = 0; r < 4; ++r) SH[wv*256 + lane*4 + r] = acc[r];
                __syncthreads();
                if (wv < 2) {
#pragma unroll
                    for (int r = 0; r < 4; ++r) {
                        float sum = SH[(wv+0)*256 + lane*4 + r] + SH[(wv+2)*256 + lane*4 + r]
                                  + SH[(wv+4)*256 + lane*4 + r] + SH[(wv+6)*256 + lane*4 + r];
                        int m = wv*16 + (lane>>4)*4 + r;
                        st_wt_u16(hAb + (size_t)t*32768 + (size_t)m*1024 + nth*16 + (lane&15),
                                  f2b(sum));
                    }
                }
            }
            __syncthreads();
            if (tid == 0) st_wt_u32(sentA + (size_t)bid*32, (u32)(t+1));
        }

        // ======== Phase B ========
        if (bid == 96) wait_publish(sentA, 96, (u32)(t+1), relA);
        else           wait_rel(relA, (u32)(t+1));
        {
            // build c_t = tanh(PEO + hA) into LDS (bf16 pairs, padded rows)
            const u32* pe = (const u32*)PEOb + (size_t)t*16384;
            const u32* ha = (const u32*)hAb + (size_t)t*16384;
#pragma unroll
            for (int ii = 0; ii < 32; ++ii) {
                int idx = tid + ii*512;
                u32 up = pe[idx], uh = ha[idx];
                float c0 = tanhf(b2f_lo(up) + b2f_lo(uh));
                float c1 = tanhf(b2f_hi(up) + b2f_hi(uh));
                int b = idx >> 9, nu = idx & 511;
                CT[b*516 + nu] = (u32)f2b(c0) | ((u32)f2b(c1) << 16);
            }
            __syncthreads();

            short8 av[16];
            if (kq4 < 2) {
                const u32* ctrow = CT + (m0d+lr)*516 + kq4*256 + (lk8 >> 1);
#pragma unroll
                for (int i = 0; i < 16; ++i) av[i] = *(const short8*)(ctrow + i*16);
            } else {
                const u16* Ab = Hd + (size_t)t*32768 + (size_t)(m0d+lr)*1024 + (kq4-2)*512 + lk8;
#pragma unroll
                for (int i = 0; i < 16; ++i) av[i] = *(const short8*)(Ab + i*32);
            }
            f32x4 acc = {0.f,0.f,0.f,0.f};
#pragma unroll
            for (int i = 0; i < 16; ++i)
                acc = __builtin_amdgcn_mfma_f32_16x16x32_bf16(av[i], wp[i], acc, 0, 0, 0);
#pragma unroll
            for (int r = 0; r < 4; ++r) SH[wv*256 + lane*4 + r] = acc[r];
            __syncthreads();
            if (wv < 2) {
                float* T = SH + 2048 + wv*272;
#pragma unroll
                for (int r = 0; r < 4; ++r) {
                    float sum = SH[(wv+0)*256 + lane*4 + r] + SH[(wv+2)*256 + lane*4 + r]
                              + SH[(wv+4)*256 + lane*4 + r] + SH[(wv+6)*256 + lane*4 + r];
                    T[((lane>>4)*4 + r)*17 + (lane&15)] = sum;
                }
                __builtin_amdgcn_sched_barrier(0);
                ushort4 xr = *(const ushort4*)(Xe + (size_t)(t*32+bbd)*4096 + bid*16 + jjq*4);
                float gi = T[b_l*17 + jjq*4 + 0] + us2f(xr.x);
                float gf = T[b_l*17 + jjq*4 + 1] + us2f(xr.y);
                float gg = T[b_l*17 + jjq*4 + 2] + us2f(xr.z);
                float go = T[b_l*17 + jjq*4 + 3] + us2f(xr.w);
                float c2 = sigf(gf)*cdec + sigf(gi)*tanhf(gg);
                float h2 = sigf(go)*tanhf(c2);
                cdec = c2;
                st_wt_u16(Hd + (size_t)(t+1)*32768 + (size_t)bbd*1024 + jd, f2b(h2));
            }
            __syncthreads();
            if (tid == 0) st_wt_u32(sentH + (size_t)bid*32, (u32)(t+1));
        }
    }
}

// ---------------- generator GEMM ----------------
__global__ __launch_bounds__(256) void k_gemm_gen(const short* __restrict__ A,
                                                  const short* __restrict__ B,
                                                  const float* __restrict__ genb,
                                                  float* __restrict__ out) {
    int wave = threadIdx.x >> 6;
    int lane = threadIdx.x & 63;
    int tile = blockIdx.x * 4 + wave;
    int mt = tile & 31;
    int nt = tile >> 5;
    int m0 = mt*64, n0 = nt*64;
    int lr = lane & 15;
    int lk = (lane >> 4)*8;
    f32x4 acc[4][4] = {};
    for (int k0 = 0; k0 < 1024; k0 += 32) {
        short8 a[4], bfr[4];
#pragma unroll
        for (int mi = 0; mi < 4; ++mi)
            a[mi] = *(const short8*)(A + (long)(m0 + mi*16 + lr)*1024 + k0 + lk);
#pragma unroll
        for (int ni = 0; ni < 4; ++ni)
            bfr[ni] = *(const short8*)(B + (long)(n0 + ni*16 + lr)*1024 + k0 + lk);
#pragma unroll
        for (int mi = 0; mi < 4; ++mi)
#pragma unroll
            for (int ni = 0; ni < 4; ++ni)
                acc[mi][ni] = __builtin_amdgcn_mfma_f32_16x16x32_bf16(a[mi], bfr[ni], acc[mi][ni], 0, 0, 0);
    }
    int dcol = lane & 15;
    int drow = (lane >> 4)*4;
#pragma unroll
    for (int mi = 0; mi < 4; ++mi) {
        int mbase = m0 + mi*16 + drow;
#pragma unroll
        for (int ni = 0; ni < 4; ++ni) {
            int n = n0 + ni*16 + dcol;
            float bv = genb[n];
            f32x4 v = acc[mi][ni];
#pragma unroll
            for (int r = 0; r < 4; ++r) {
                int m = mbase + r;
                if (m < 2016) out[(long)(m + 32)*32000 + n] = v[r] + bv;
            }
        }
    }
}

// ---------------- log-softmax ----------------
__global__ __launch_bounds__(256) void k_lsm(float* __restrict__ out) {
    long row = 32 + blockIdx.x;
    float* p = out + row*32000L;
    float4* p4 = (float4*)p;
    int tid = threadIdx.x;
    __shared__ float sm[4];
    __shared__ float ss[4];
    float m = -1e30f;
    for (int i = tid; i < 8000; i += 256) {
        float4 v = p4[i];
        m = fmaxf(m, fmaxf(fmaxf(v.x, v.y), fmaxf(v.z, v.w)));
    }
    for (int off = 32; off; off >>= 1) m = fmaxf(m, __shfl_xor(m, off));
    if ((tid & 63) == 0) sm[tid >> 6] = m;
    __syncthreads();
    m = fmaxf(fmaxf(sm[0], sm[1]), fmaxf(sm[2], sm[3]));
    float s = 0;
    for (int i = tid; i < 8000; i += 256) {
        float4 v = p4[i];
        s += expf(v.x - m) + expf(v.y - m) + expf(v.z - m) + expf(v.w - m);
    }
    for (int off = 32; off; off >>= 1) s += __shfl_xor(s, off);
    if ((tid & 63) == 0) ss[tid >> 6] = s;
    __syncthreads();
    s = ss[0] + ss[1] + ss[2] + ss[3];
    float lse = m + logf(s);
    for (int i = tid; i < 8000; i += 256) {
        float4 v = p4[i];
        v.x -= lse; v.y -= lse; v.z -= lse; v.w -= lse;
        p4[i] = v;
    }
}

// ---------------- launch ----------------

extern "C" void kernel_launch(void* const* d_in, const int* in_sizes, int n_in,
                              void* d_out, int out_size, void* d_ws, size_t ws_size,
                              hipStream_t stream) {
    const float* eemb  = (const float*)d_in[0];
    const float* ewihf = (const float*)d_in[1];
    const float* ewhhf = (const float*)d_in[2];
    const float* ebf   = (const float*)d_in[3];
    const float* ewihb = (const float*)d_in[4];
    const float* ewhhb = (const float*)d_in[5];
    const float* ebb   = (const float*)d_in[6];
    const float* awi   = (const float*)d_in[7];
    const float* awo   = (const float*)d_in[8];
    const float* dwih  = (const float*)d_in[9];
    const float* dwhh  = (const float*)d_in[10];
    const float* db    = (const float*)d_in[11];
    const float* demb  = (const float*)d_in[12];
    const float* genw  = (const float*)d_in[13];
    const float* genb  = (const float*)d_in[14];
    const int* srci    = (const int*)d_in[15];
    const int* trgi    = (const int*)d_in[16];
    float* out = (float*)d_out;

    float* F = (float*)d_ws;
    u32* S       = (u32*)F;
    u32* sentE   = S;                      // 64 x 32
    u32* sentA   = S + 2048;               // 96 x 32
    u32* sentH   = S + 5120;               // 256 x 32
    u32* relE    = S + 13312;              // 4 x 32
    u32* relA    = S + 13440;              // 32
    u32* relH    = S + 13472;              // 32
    u32* pingw   = S + 13504;              // 32
    u32* pongw   = S + 13536;              // 32
    float* cfin  = F + 16384;              // 32768 floats
    u16*   U     = (u16*)(F + 49152);

    u16* Xf_    = U;                       // 2048x2048
    u16* Xb_    = U + 4194304u;            // 2048x2048
    u16* Xe_    = U + 8388608u;            // 2016x4096
    u16* WencB  = U + 16646144u;           // 2 x 2048x512
    u16* awiTB  = U + 18743296u;           // 1024x1024
    u16* awoB   = U + 19791872u;           // 1024x2048
    u16* WdecB  = U + 21889024u;           // 4096x2048
    u16* genw_b = U + 30277632u;           // 32000x1024
    u16* encBX  = U + 63045632u;           // 65 x 32x1024
    u16* Hd     = U + 65175552u;           // 65 x 32x1024
    u16* PEOb   = U + 67305472u;           // 63 x 32x1024
    u16* hAb    = U + 69369856u;           // 63 x 32x1024
    u16* encPB  = U + 71434240u;           // 2048x1024
    u16* EOAb   = U + 73531392u;           // 32 x 64 x 1024

    k_zero<<<64, 256, 0, stream>>>(F, 16384);          // sentinels + rel + ping/pong
    k_ping<<<2, 64, 0, stream>>>(pingw, pongw);        // DIAGNOSTIC: dur/512 = hop
    k_zero<<<64, 256, 0, stream>>>((float*)encBX, 16384);
    k_zero<<<2048, 256, 0, stream>>>(out, 1024000L);

    k_xw<<<dim3(32, 64), 256, 0, stream>>>(eemb, srci, ewihf, 300, 0, ebf, Xf_, 2048, 511, 9);
    k_xw<<<dim3(32, 64), 256, 0, stream>>>(eemb, srci, ewihb, 300, 0, ebb, Xb_, 2048, 511, 9);
    k_xw<<<dim3(64, 63), 256, 0, stream>>>(demb, trgi, dwih, 1324, 1024, db, Xe_, 4096, 1023, 10);

    k_wenc<<<4096, 256, 0, stream>>>(ewhhf, WencB);
    k_wenc<<<4096, 256, 0, stream>>>(ewhhb, WencB + 1048576u);
    k_awiT<<<4096, 256, 0, stream>>>(awi, awiTB);
    k_f2b<<<2048, 256, 0, stream>>>((const float4*)awo, (ushort4*)awoB, 524288L);
    k_wdec<<<8192, 256, 0, stream>>>(dwih, dwhh, WdecB);
    k_f2b<<<8192, 256, 0, stream>>>((const float4*)genw, (ushort4*)genw_b, 8192000L);

    k_enc<<<64, 512, 0, stream>>>(Xf_, Xb_, WencB, encBX, cfin, sentE, relE);
    k_pack<<<64, 256, 0, stream>>>(encBX, Hd);
    k_mid<<<1024, 256, 0, stream>>>(encBX, awiTB, awoB, encPB, EOAb);
    k_dec<<<256, 512, 0, stream>>>(Xe_, awoB, WdecB, encPB, EOAb,
                                   Hd, PEOb, hAb, cfin,
                                   sentA, sentH, relA, relH);

    k_gemm_gen<<<4000, 256, 0, stream>>>((const short*)(Hd + 32768u), (const short*)genw_b, genb, out);
    k_lsm<<<2016, 256, 0, stream>>>(out);
}